// Round 2
// baseline (8714.610 us; speedup 1.0000x reference)
//
#include <hip/hip_runtime.h>

#define N_NODES 100000
#define N_EDGES 1600000
#define HIDDEN  128
#define OUTF    64

// ---------------- zero (float4 grid-stride) ----------------
__global__ void zero_kernel(float4* p, int n4) {
    int i = blockIdx.x * blockDim.x + threadIdx.x;
    if (i < n4) p[i] = make_float4(0.f, 0.f, 0.f, 0.f);
}

// ---------------- degree via atomics ----------------
__global__ void degree_kernel(const int* __restrict__ row, float* __restrict__ deg) {
    int e = blockIdx.x * blockDim.x + threadIdx.x;
    if (e < N_EDGES) atomicAdd(&deg[row[e]], 1.0f);
}

// ---------------- deg -> rsqrt(clamp(deg,1)) in place ----------------
__global__ void dinv_kernel(float* __restrict__ deg) {
    int i = blockIdx.x * blockDim.x + threadIdx.x;
    if (i < N_NODES) deg[i] = rsqrtf(fmaxf(deg[i], 1.0f));
}

// ---------------- per-edge norm ----------------
__global__ void norm_kernel(const int* __restrict__ ei,
                            const float* __restrict__ dinv,
                            float* __restrict__ norm) {
    int e = blockIdx.x * blockDim.x + threadIdx.x;
    if (e < N_EDGES) {
        int r = ei[e];
        int c = ei[N_EDGES + e];
        norm[e] = dinv[r] * dinv[c];
    }
}

// ---------------- push scatter: hdst[row] += norm * hsrc[col] ----------------
// 32 threads per edge; each thread handles 4 consecutive floats (float4 gather).
__global__ __launch_bounds__(256) void scatter_kernel(const int* __restrict__ ei,
                                                      const float* __restrict__ norm,
                                                      const float* __restrict__ hsrc,
                                                      float* __restrict__ hdst) {
    long long gid = (long long)blockIdx.x * blockDim.x + threadIdx.x;
    int e    = (int)(gid >> 5);
    int lane = (int)(gid & 31);
    if (e >= N_EDGES) return;
    int r = ei[e];             // destination
    int c = ei[N_EDGES + e];   // source
    float w = norm[e];
    const float4* src = (const float4*)(hsrc + (size_t)c * HIDDEN);
    float4 v = src[lane];
    float* dst = hdst + (size_t)r * HIDDEN + lane * 4;
    atomicAdd(dst + 0, v.x * w);
    atomicAdd(dst + 1, v.y * w);
    atomicAdd(dst + 2, v.z * w);
    atomicAdd(dst + 3, v.w * w);
}

// ---------------- accumulating projection: out (+)= 0.25 * h @ W^T (+ b) ----------------
// Block: 256 threads -> 16 rows x 64 cols. W^T staged in LDS (32KB), h rows in LDS
// (stride 132 to break the 4-way bank conflict on the broadcast read).
#define HPAD 132
__global__ __launch_bounds__(256) void gemm_kernel(const float* __restrict__ h,
                                                   const float* __restrict__ W,
                                                   const float* __restrict__ b,
                                                   float* __restrict__ out,
                                                   int init) {
    __shared__ float wt[HIDDEN * OUTF];   // [k][o]
    __shared__ float hs[16 * HPAD];       // [r][k] padded
    int tid = threadIdx.x;

    for (int i = tid; i < HIDDEN * OUTF; i += 256) {
        int o = i / HIDDEN, k = i % HIDDEN;   // W row-major [o][k]
        wt[k * OUTF + o] = W[i];
    }
    int rowBase = blockIdx.x * 16;
    for (int i = tid; i < 16 * HIDDEN; i += 256) {
        int r = i / HIDDEN, k = i % HIDDEN;
        hs[r * HPAD + k] = h[(size_t)(rowBase + r) * HIDDEN + k];
    }
    __syncthreads();

    int o4 = (tid & 15) * 4;
    int r  = tid >> 4;
    float4 acc = make_float4(0.f, 0.f, 0.f, 0.f);
    #pragma unroll 8
    for (int k = 0; k < HIDDEN; ++k) {
        float  hv = hs[r * HPAD + k];
        float4 wv = *(const float4*)&wt[k * OUTF + o4];
        acc.x += hv * wv.x;
        acc.y += hv * wv.y;
        acc.z += hv * wv.z;
        acc.w += hv * wv.w;
    }
    acc.x *= 0.25f; acc.y *= 0.25f; acc.z *= 0.25f; acc.w *= 0.25f;

    size_t n = (size_t)(rowBase + r);
    float4* op = (float4*)(out + n * OUTF + o4);
    if (init) {
        const float4 bv = *(const float4*)(b + o4);
        acc.x += bv.x; acc.y += bv.y; acc.z += bv.z; acc.w += bv.w;
        *op = acc;
    } else {
        float4 old = *op;
        acc.x += old.x; acc.y += old.y; acc.z += old.z; acc.w += old.w;
        *op = acc;
    }
}

extern "C" void kernel_launch(void* const* d_in, const int* in_sizes, int n_in,
                              void* d_out, int out_size, void* d_ws, size_t ws_size,
                              hipStream_t stream) {
    const float* x  = (const float*)d_in[0];
    const int*   ei = (const int*)d_in[1];     // int32 per harness contract, [2, E] flat
    const float* W  = (const float*)d_in[2];
    const float* b  = (const float*)d_in[3];
    float*       out = (float*)d_out;

    // workspace layout
    float* A    = (float*)d_ws;                 // N*H
    float* B    = A + (size_t)N_NODES * HIDDEN; // N*H
    float* norm = B + (size_t)N_NODES * HIDDEN; // E
    float* deg  = norm + N_EDGES;               // N

    const int BLK = 256;
    const int degBlocks  = (N_EDGES + BLK - 1) / BLK;
    const int nodeBlocks = (N_NODES + BLK - 1) / BLK;
    const int featZero4  = (N_NODES * HIDDEN / 4 + BLK - 1) / BLK;
    const int degZero4   = (N_NODES / 4 + BLK - 1) / BLK;
    const int scatBlocks = (int)(((size_t)N_EDGES * 32 + BLK - 1) / BLK);
    const int gemmBlocks = N_NODES / 16;  // 6250, exact

    // degrees + norms
    zero_kernel<<<degZero4, BLK, 0, stream>>>((float4*)deg, N_NODES / 4);
    degree_kernel<<<degBlocks, BLK, 0, stream>>>(ei, deg);
    dinv_kernel<<<nodeBlocks, BLK, 0, stream>>>(deg);
    norm_kernel<<<degBlocks, BLK, 0, stream>>>(ei, deg, norm);

    // layer 1: A = prop(x);  out = b + 0.25*(x + A)@Wt (two passes)
    zero_kernel<<<featZero4, BLK, 0, stream>>>((float4*)A, N_NODES * HIDDEN / 4);
    scatter_kernel<<<scatBlocks, BLK, 0, stream>>>(ei, norm, x, A);
    gemm_kernel<<<gemmBlocks, BLK, 0, stream>>>(x, W, b, out, 1);
    gemm_kernel<<<gemmBlocks, BLK, 0, stream>>>(A, W, b, out, 0);

    // layer 2: B = prop(A); out += 0.25*B@Wt
    zero_kernel<<<featZero4, BLK, 0, stream>>>((float4*)B, N_NODES * HIDDEN / 4);
    scatter_kernel<<<scatBlocks, BLK, 0, stream>>>(ei, norm, A, B);
    gemm_kernel<<<gemmBlocks, BLK, 0, stream>>>(B, W, b, out, 0);

    // layer 3: A = prop(B); out += 0.25*A@Wt
    zero_kernel<<<featZero4, BLK, 0, stream>>>((float4*)A, N_NODES * HIDDEN / 4);
    scatter_kernel<<<scatBlocks, BLK, 0, stream>>>(ei, norm, B, A);
    gemm_kernel<<<gemmBlocks, BLK, 0, stream>>>(A, W, b, out, 0);
}

// Round 3
// 1438.649 us; speedup vs baseline: 6.0575x; 6.0575x over previous
//
#include <hip/hip_runtime.h>

#define N_NODES 100000
#define N_EDGES 1600000
#define HIDDEN  128
#define OUTF    64

// ---------------- zero ints ----------------
__global__ void zero_kernel(int4* p, int n4) {
    int i = blockIdx.x * blockDim.x + threadIdx.x;
    if (i < n4) p[i] = make_int4(0, 0, 0, 0);
}

// ---------------- count destination degrees (int atomics) ----------------
__global__ void count_kernel(const int* __restrict__ ei, int* __restrict__ cnt) {
    int e = blockIdx.x * blockDim.x + threadIdx.x;
    if (e < N_EDGES) atomicAdd(&cnt[ei[e]], 1);
}

// ---------------- single-block scan: cnt -> rowptr (exclusive), dinv, zero cnt ----------------
__global__ __launch_bounds__(1024) void scan_kernel(int* __restrict__ cnt,
                                                    int* __restrict__ rowptr,
                                                    float* __restrict__ dinv) {
    __shared__ int partial[1024];
    int tid = threadIdx.x;
    const int CH = (N_NODES + 1023) / 1024;  // 98
    int base = tid * CH;
    int sum = 0;
    for (int i = 0; i < CH; ++i) {
        int idx = base + i;
        if (idx < N_NODES) sum += cnt[idx];
    }
    partial[tid] = sum;
    __syncthreads();
    for (int off = 1; off < 1024; off <<= 1) {
        int t = (tid >= off) ? partial[tid - off] : 0;
        __syncthreads();
        partial[tid] += t;
        __syncthreads();
    }
    int run = partial[tid] - sum;  // exclusive offset of this chunk
    for (int i = 0; i < CH; ++i) {
        int idx = base + i;
        if (idx < N_NODES) {
            int c = cnt[idx];
            rowptr[idx] = run;
            dinv[idx] = rsqrtf(fmaxf((float)c, 1.0f));
            cnt[idx] = 0;  // re-zero for use as fill cursor
            run += c;
        }
    }
    if (tid == 1023) rowptr[N_NODES] = run;
}

// ---------------- fill CSR column array ----------------
__global__ void fill_kernel(const int* __restrict__ ei,
                            const int* __restrict__ rowptr,
                            int* __restrict__ cursor,
                            int* __restrict__ csr_col) {
    int e = blockIdx.x * blockDim.x + threadIdx.x;
    if (e < N_EDGES) {
        int r = ei[e];
        int c = ei[N_EDGES + e];
        int pos = rowptr[r] + atomicAdd(&cursor[r], 1);
        csr_col[pos] = c;
    }
}

// ---------------- pull propagate: one wave (64 lanes) per destination node ----------------
// hdst[n] = dinv[n] * sum_{c in adj(n)} dinv[c] * hsrc[c]
__global__ __launch_bounds__(256) void pull_kernel(const int* __restrict__ rowptr,
                                                   const int* __restrict__ csr_col,
                                                   const float* __restrict__ dinv,
                                                   const float* __restrict__ hsrc,
                                                   float* __restrict__ hdst) {
    int node = blockIdx.x * 4 + (threadIdx.x >> 6);
    int lane = threadIdx.x & 63;
    if (node >= N_NODES) return;
    int s = rowptr[node];
    int e = rowptr[node + 1];
    float dr = dinv[node];
    float2 acc = make_float2(0.f, 0.f);
    int i = s;
    // 2-way manual unroll for load ILP
    for (; i + 1 < e; i += 2) {
        int c0 = csr_col[i];
        int c1 = csr_col[i + 1];
        float w0 = dinv[c0];
        float w1 = dinv[c1];
        float2 v0 = *(const float2*)(hsrc + (size_t)c0 * HIDDEN + lane * 2);
        float2 v1 = *(const float2*)(hsrc + (size_t)c1 * HIDDEN + lane * 2);
        acc.x += w0 * v0.x + w1 * v1.x;
        acc.y += w0 * v0.y + w1 * v1.y;
    }
    if (i < e) {
        int c0 = csr_col[i];
        float w0 = dinv[c0];
        float2 v0 = *(const float2*)(hsrc + (size_t)c0 * HIDDEN + lane * 2);
        acc.x += w0 * v0.x;
        acc.y += w0 * v0.y;
    }
    acc.x *= dr; acc.y *= dr;
    *(float2*)(hdst + (size_t)node * HIDDEN + lane * 2) = acc;
}

// ---------------- accumulating projection: out (+)= 0.25 * h @ W^T (+ b) ----------------
#define HPAD 132
__global__ __launch_bounds__(256) void gemm_kernel(const float* __restrict__ h,
                                                   const float* __restrict__ W,
                                                   const float* __restrict__ b,
                                                   float* __restrict__ out,
                                                   int init) {
    __shared__ float wt[HIDDEN * OUTF];   // [k][o]
    __shared__ float hs[16 * HPAD];       // [r][k] padded
    int tid = threadIdx.x;

    for (int i = tid; i < HIDDEN * OUTF; i += 256) {
        int o = i / HIDDEN, k = i % HIDDEN;   // W row-major [o][k]
        wt[k * OUTF + o] = W[i];
    }
    int rowBase = blockIdx.x * 16;
    for (int i = tid; i < 16 * HIDDEN; i += 256) {
        int r = i / HIDDEN, k = i % HIDDEN;
        hs[r * HPAD + k] = h[(size_t)(rowBase + r) * HIDDEN + k];
    }
    __syncthreads();

    int o4 = (tid & 15) * 4;
    int r  = tid >> 4;
    float4 acc = make_float4(0.f, 0.f, 0.f, 0.f);
    #pragma unroll 8
    for (int k = 0; k < HIDDEN; ++k) {
        float  hv = hs[r * HPAD + k];
        float4 wv = *(const float4*)&wt[k * OUTF + o4];
        acc.x += hv * wv.x;
        acc.y += hv * wv.y;
        acc.z += hv * wv.z;
        acc.w += hv * wv.w;
    }
    acc.x *= 0.25f; acc.y *= 0.25f; acc.z *= 0.25f; acc.w *= 0.25f;

    size_t n = (size_t)(rowBase + r);
    float4* op = (float4*)(out + n * OUTF + o4);
    if (init) {
        const float4 bv = *(const float4*)(b + o4);
        acc.x += bv.x; acc.y += bv.y; acc.z += bv.z; acc.w += bv.w;
        *op = acc;
    } else {
        float4 old = *op;
        acc.x += old.x; acc.y += old.y; acc.z += old.z; acc.w += old.w;
        *op = acc;
    }
}

extern "C" void kernel_launch(void* const* d_in, const int* in_sizes, int n_in,
                              void* d_out, int out_size, void* d_ws, size_t ws_size,
                              hipStream_t stream) {
    const float* x  = (const float*)d_in[0];
    const int*   ei = (const int*)d_in[1];     // int32, [2, E] flat
    const float* W  = (const float*)d_in[2];
    const float* b  = (const float*)d_in[3];
    float*       out = (float*)d_out;

    // workspace layout (floats/ints are 4B)
    float* A      = (float*)d_ws;                    // N*H
    float* B      = A + (size_t)N_NODES * HIDDEN;    // N*H
    int*   csrcol = (int*)(B + (size_t)N_NODES * HIDDEN);  // E
    int*   rowptr = csrcol + N_EDGES;                // N+1
    int*   cnt    = rowptr + (N_NODES + 1);          // N (counts, then fill cursor)
    float* dinv   = (float*)(cnt + N_NODES);         // N

    const int BLK = 256;
    const int edgeBlocks = (N_EDGES + BLK - 1) / BLK;
    const int cntZero4   = (N_NODES / 4 + BLK - 1) / BLK;
    const int pullBlocks = (N_NODES + 3) / 4;        // 4 nodes (waves) per block
    const int gemmBlocks = N_NODES / 16;             // 6250, exact

    // ---- CSR build ----
    zero_kernel<<<cntZero4, BLK, 0, stream>>>((int4*)cnt, N_NODES / 4);
    count_kernel<<<edgeBlocks, BLK, 0, stream>>>(ei, cnt);
    scan_kernel<<<1, 1024, 0, stream>>>(cnt, rowptr, dinv);   // also zeroes cnt -> cursor
    fill_kernel<<<edgeBlocks, BLK, 0, stream>>>(ei, rowptr, cnt, csrcol);

    // ---- layers + fused mean/projection ----
    // out = b + 0.25*x@Wt
    gemm_kernel<<<gemmBlocks, BLK, 0, stream>>>(x, W, b, out, 1);
    // A = prop(x); out += 0.25*A@Wt
    pull_kernel<<<pullBlocks, BLK, 0, stream>>>(rowptr, csrcol, dinv, x, A);
    gemm_kernel<<<gemmBlocks, BLK, 0, stream>>>(A, W, b, out, 0);
    // B = prop(A); out += 0.25*B@Wt
    pull_kernel<<<pullBlocks, BLK, 0, stream>>>(rowptr, csrcol, dinv, A, B);
    gemm_kernel<<<gemmBlocks, BLK, 0, stream>>>(B, W, b, out, 0);
    // A = prop(B); out += 0.25*A@Wt   (reads B, writes A — no hazard)
    pull_kernel<<<pullBlocks, BLK, 0, stream>>>(rowptr, csrcol, dinv, B, A);
    gemm_kernel<<<gemmBlocks, BLK, 0, stream>>>(A, W, b, out, 0);
}

// Round 4
// 1094.256 us; speedup vs baseline: 7.9640x; 1.3147x over previous
//
#include <hip/hip_runtime.h>

#define N_NODES 100000
#define N_EDGES 1600000
#define HIDDEN  128
#define OUTF    64
#define TILE    1024
#define NTILES  ((N_NODES + TILE - 1) / TILE)   // 98

// ---------------- zero ints ----------------
__global__ void zero_kernel(int4* p, int n4) {
    int i = blockIdx.x * blockDim.x + threadIdx.x;
    if (i < n4) p[i] = make_int4(0, 0, 0, 0);
}

// ---------------- count destination degrees (int atomics) ----------------
__global__ void count_kernel(const int* __restrict__ ei, int* __restrict__ cnt) {
    int e = blockIdx.x * blockDim.x + threadIdx.x;
    if (e < N_EDGES) atomicAdd(&cnt[ei[e]], 1);
}

// ---------------- scan stage 1: per-tile exclusive scan (1024 elems / 256-thread block) ----------------
__global__ __launch_bounds__(256) void scan_tiles_kernel(const int* __restrict__ cnt,
                                                         int* __restrict__ rowptr,
                                                         int* __restrict__ tileSum) {
    __shared__ int ps[256];
    int tid  = threadIdx.x;
    int base = blockIdx.x * TILE + tid * 4;
    int a0 = 0, a1 = 0, a2 = 0, a3 = 0;
    if (base + 3 < N_NODES) {
        int4 v = *(const int4*)(cnt + base);
        a0 = v.x; a1 = v.y; a2 = v.z; a3 = v.w;
    } else {
        if (base + 0 < N_NODES) a0 = cnt[base + 0];
        if (base + 1 < N_NODES) a1 = cnt[base + 1];
        if (base + 2 < N_NODES) a2 = cnt[base + 2];
        if (base + 3 < N_NODES) a3 = cnt[base + 3];
    }
    int s = a0 + a1 + a2 + a3;
    ps[tid] = s;
    __syncthreads();
    for (int off = 1; off < 256; off <<= 1) {
        int t = (tid >= off) ? ps[tid - off] : 0;
        __syncthreads();
        ps[tid] += t;
        __syncthreads();
    }
    int ex = ps[tid] - s;  // exclusive prefix within tile
    int e0 = ex, e1 = e0 + a0, e2 = e1 + a1, e3 = e2 + a2;
    if (base + 3 < N_NODES) {
        *(int4*)(rowptr + base) = make_int4(e0, e1, e2, e3);
    } else {
        if (base + 0 < N_NODES) rowptr[base + 0] = e0;
        if (base + 1 < N_NODES) rowptr[base + 1] = e1;
        if (base + 2 < N_NODES) rowptr[base + 2] = e2;
        if (base + 3 < N_NODES) rowptr[base + 3] = e3;
    }
    if (tid == 255) tileSum[blockIdx.x] = ps[255];
}

// ---------------- scan stage 2: scan the 98 tile sums (single small block) ----------------
__global__ __launch_bounds__(128) void scan_sums_kernel(const int* __restrict__ tileSum,
                                                        int* __restrict__ tileOff,
                                                        int* __restrict__ rowptr) {
    __shared__ int ps[128];
    int tid = threadIdx.x;
    int v = (tid < NTILES) ? tileSum[tid] : 0;
    ps[tid] = v;
    __syncthreads();
    for (int off = 1; off < 128; off <<= 1) {
        int t = (tid >= off) ? ps[tid - off] : 0;
        __syncthreads();
        ps[tid] += t;
        __syncthreads();
    }
    if (tid < NTILES) tileOff[tid] = ps[tid] - v;
    if (tid == 127) rowptr[N_NODES] = ps[127];  // total = N_EDGES
}

// ---------------- scan stage 3: add tile offsets, compute dinv, zero cursor ----------------
__global__ void finalize_kernel(const int* __restrict__ cnt,
                                const int* __restrict__ tileOff,
                                int* __restrict__ rowptr,
                                float* __restrict__ dinv,
                                int* __restrict__ cursor) {
    int i = blockIdx.x * blockDim.x + threadIdx.x;
    if (i < N_NODES) {
        rowptr[i] += tileOff[i / TILE];
        dinv[i]    = rsqrtf(fmaxf((float)cnt[i], 1.0f));
        cursor[i]  = 0;
    }
}

// ---------------- fill CSR column array ----------------
__global__ void fill_kernel(const int* __restrict__ ei,
                            const int* __restrict__ rowptr,
                            int* __restrict__ cursor,
                            int* __restrict__ csr_col) {
    int e = blockIdx.x * blockDim.x + threadIdx.x;
    if (e < N_EDGES) {
        int r = ei[e];
        int c = ei[N_EDGES + e];
        int pos = rowptr[r] + atomicAdd(&cursor[r], 1);
        csr_col[pos] = c;
    }
}

// ---------------- pull propagate: one wave (64 lanes) per destination node ----------------
// hdst[n] = dinv[n] * sum_{c in adj(n)} dinv[c] * hsrc[c]
__global__ __launch_bounds__(256) void pull_kernel(const int* __restrict__ rowptr,
                                                   const int* __restrict__ csr_col,
                                                   const float* __restrict__ dinv,
                                                   const float* __restrict__ hsrc,
                                                   float* __restrict__ hdst) {
    int node = blockIdx.x * 4 + (threadIdx.x >> 6);
    int lane = threadIdx.x & 63;
    if (node >= N_NODES) return;
    int s = rowptr[node];
    int e = rowptr[node + 1];
    float dr = dinv[node];
    float2 acc = make_float2(0.f, 0.f);
    int i = s;
    // 4-way unroll: 4 independent col->dinv/row load chains in flight
    for (; i + 3 < e; i += 4) {
        int c0 = csr_col[i];
        int c1 = csr_col[i + 1];
        int c2 = csr_col[i + 2];
        int c3 = csr_col[i + 3];
        float w0 = dinv[c0], w1 = dinv[c1], w2 = dinv[c2], w3 = dinv[c3];
        float2 v0 = *(const float2*)(hsrc + (size_t)c0 * HIDDEN + lane * 2);
        float2 v1 = *(const float2*)(hsrc + (size_t)c1 * HIDDEN + lane * 2);
        float2 v2 = *(const float2*)(hsrc + (size_t)c2 * HIDDEN + lane * 2);
        float2 v3 = *(const float2*)(hsrc + (size_t)c3 * HIDDEN + lane * 2);
        acc.x += w0 * v0.x + w1 * v1.x;
        acc.y += w0 * v0.y + w1 * v1.y;
        acc.x += w2 * v2.x + w3 * v3.x;
        acc.y += w2 * v2.y + w3 * v3.y;
    }
    for (; i < e; ++i) {
        int c0 = csr_col[i];
        float w0 = dinv[c0];
        float2 v0 = *(const float2*)(hsrc + (size_t)c0 * HIDDEN + lane * 2);
        acc.x += w0 * v0.x;
        acc.y += w0 * v0.y;
    }
    acc.x *= dr; acc.y *= dr;
    *(float2*)(hdst + (size_t)node * HIDDEN + lane * 2) = acc;
}

// ---------------- accumulating projection: out (+)= 0.25 * h @ W^T (+ b) ----------------
#define HPAD 132
__global__ __launch_bounds__(256) void gemm_kernel(const float* __restrict__ h,
                                                   const float* __restrict__ W,
                                                   const float* __restrict__ b,
                                                   float* __restrict__ out,
                                                   int init) {
    __shared__ float wt[HIDDEN * OUTF];   // [k][o]
    __shared__ float hs[16 * HPAD];       // [r][k] padded
    int tid = threadIdx.x;

    for (int i = tid; i < HIDDEN * OUTF; i += 256) {
        int o = i / HIDDEN, k = i % HIDDEN;   // W row-major [o][k]
        wt[k * OUTF + o] = W[i];
    }
    int rowBase = blockIdx.x * 16;
    for (int i = tid; i < 16 * HIDDEN; i += 256) {
        int r = i / HIDDEN, k = i % HIDDEN;
        hs[r * HPAD + k] = h[(size_t)(rowBase + r) * HIDDEN + k];
    }
    __syncthreads();

    int o4 = (tid & 15) * 4;
    int r  = tid >> 4;
    float4 acc = make_float4(0.f, 0.f, 0.f, 0.f);
    #pragma unroll 8
    for (int k = 0; k < HIDDEN; ++k) {
        float  hv = hs[r * HPAD + k];
        float4 wv = *(const float4*)&wt[k * OUTF + o4];
        acc.x += hv * wv.x;
        acc.y += hv * wv.y;
        acc.z += hv * wv.z;
        acc.w += hv * wv.w;
    }
    acc.x *= 0.25f; acc.y *= 0.25f; acc.z *= 0.25f; acc.w *= 0.25f;

    size_t n = (size_t)(rowBase + r);
    float4* op = (float4*)(out + n * OUTF + o4);
    if (init) {
        const float4 bv = *(const float4*)(b + o4);
        acc.x += bv.x; acc.y += bv.y; acc.z += bv.z; acc.w += bv.w;
        *op = acc;
    } else {
        float4 old = *op;
        acc.x += old.x; acc.y += old.y; acc.z += old.z; acc.w += old.w;
        *op = acc;
    }
}

extern "C" void kernel_launch(void* const* d_in, const int* in_sizes, int n_in,
                              void* d_out, int out_size, void* d_ws, size_t ws_size,
                              hipStream_t stream) {
    const float* x  = (const float*)d_in[0];
    const int*   ei = (const int*)d_in[1];     // int32, [2, E] flat
    const float* W  = (const float*)d_in[2];
    const float* b  = (const float*)d_in[3];
    float*       out = (float*)d_out;

    // workspace layout (4B elements)
    float* A       = (float*)d_ws;                          // N*H
    float* B       = A + (size_t)N_NODES * HIDDEN;          // N*H
    int*   csrcol  = (int*)(B + (size_t)N_NODES * HIDDEN);  // E
    int*   rowptr  = csrcol + N_EDGES;                      // N+1
    int*   cnt     = rowptr + (N_NODES + 1);                // N (counts, then fill cursor)
    float* dinv    = (float*)(cnt + N_NODES);               // N
    int*   tileSum = (int*)(dinv + N_NODES);                // NTILES
    int*   tileOff = tileSum + NTILES;                      // NTILES

    const int BLK = 256;
    const int edgeBlocks = (N_EDGES + BLK - 1) / BLK;
    const int nodeBlocks = (N_NODES + BLK - 1) / BLK;
    const int cntZero4   = (N_NODES / 4 + BLK - 1) / BLK;
    const int pullBlocks = (N_NODES + 3) / 4;        // 4 nodes (waves) per block
    const int gemmBlocks = N_NODES / 16;             // 6250, exact

    // ---- CSR build ----
    zero_kernel<<<cntZero4, BLK, 0, stream>>>((int4*)cnt, N_NODES / 4);
    count_kernel<<<edgeBlocks, BLK, 0, stream>>>(ei, cnt);
    scan_tiles_kernel<<<NTILES, BLK, 0, stream>>>(cnt, rowptr, tileSum);
    scan_sums_kernel<<<1, 128, 0, stream>>>(tileSum, tileOff, rowptr);
    finalize_kernel<<<nodeBlocks, BLK, 0, stream>>>(cnt, tileOff, rowptr, dinv, cnt);
    fill_kernel<<<edgeBlocks, BLK, 0, stream>>>(ei, rowptr, cnt, csrcol);

    // ---- layers + fused mean/projection ----
    // out = b + 0.25*x@Wt
    gemm_kernel<<<gemmBlocks, BLK, 0, stream>>>(x, W, b, out, 1);
    // A = prop(x); out += 0.25*A@Wt
    pull_kernel<<<pullBlocks, BLK, 0, stream>>>(rowptr, csrcol, dinv, x, A);
    gemm_kernel<<<gemmBlocks, BLK, 0, stream>>>(A, W, b, out, 0);
    // B = prop(A); out += 0.25*B@Wt
    pull_kernel<<<pullBlocks, BLK, 0, stream>>>(rowptr, csrcol, dinv, A, B);
    gemm_kernel<<<gemmBlocks, BLK, 0, stream>>>(B, W, b, out, 0);
    // A = prop(B); out += 0.25*A@Wt   (reads B, writes A — no hazard)
    pull_kernel<<<pullBlocks, BLK, 0, stream>>>(rowptr, csrcol, dinv, B, A);
    gemm_kernel<<<gemmBlocks, BLK, 0, stream>>>(A, W, b, out, 0);
}

// Round 5
// 539.560 us; speedup vs baseline: 16.1513x; 2.0281x over previous
//
#include <hip/hip_runtime.h>

#define N_NODES 100000
#define N_EDGES 1600000
#define HIDDEN  128
#define OUTF    64
#define TILE    1024
#define NTILES  ((N_NODES + TILE - 1) / TILE)   // 98

// ---------------- zero ints ----------------
__global__ void zero_kernel(int4* p, int n4) {
    int i = blockIdx.x * blockDim.x + threadIdx.x;
    if (i < n4) p[i] = make_int4(0, 0, 0, 0);
}

// ---------------- count destination degrees (int atomics) ----------------
__global__ void count_kernel(const int* __restrict__ ei, int* __restrict__ cnt) {
    int e = blockIdx.x * blockDim.x + threadIdx.x;
    if (e < N_EDGES) atomicAdd(&cnt[ei[e]], 1);
}

// ---------------- scan stage 1: per-tile exclusive scan ----------------
__global__ __launch_bounds__(256) void scan_tiles_kernel(const int* __restrict__ cnt,
                                                         int* __restrict__ rowptr,
                                                         int* __restrict__ tileSum) {
    __shared__ int ps[256];
    int tid  = threadIdx.x;
    int base = blockIdx.x * TILE + tid * 4;
    int a0 = 0, a1 = 0, a2 = 0, a3 = 0;
    if (base + 3 < N_NODES) {
        int4 v = *(const int4*)(cnt + base);
        a0 = v.x; a1 = v.y; a2 = v.z; a3 = v.w;
    } else {
        if (base + 0 < N_NODES) a0 = cnt[base + 0];
        if (base + 1 < N_NODES) a1 = cnt[base + 1];
        if (base + 2 < N_NODES) a2 = cnt[base + 2];
        if (base + 3 < N_NODES) a3 = cnt[base + 3];
    }
    int s = a0 + a1 + a2 + a3;
    ps[tid] = s;
    __syncthreads();
    for (int off = 1; off < 256; off <<= 1) {
        int t = (tid >= off) ? ps[tid - off] : 0;
        __syncthreads();
        ps[tid] += t;
        __syncthreads();
    }
    int ex = ps[tid] - s;
    int e0 = ex, e1 = e0 + a0, e2 = e1 + a1, e3 = e2 + a2;
    if (base + 3 < N_NODES) {
        *(int4*)(rowptr + base) = make_int4(e0, e1, e2, e3);
    } else {
        if (base + 0 < N_NODES) rowptr[base + 0] = e0;
        if (base + 1 < N_NODES) rowptr[base + 1] = e1;
        if (base + 2 < N_NODES) rowptr[base + 2] = e2;
        if (base + 3 < N_NODES) rowptr[base + 3] = e3;
    }
    if (tid == 255) tileSum[blockIdx.x] = ps[255];
}

// ---------------- scan stage 2: scan tile sums ----------------
__global__ __launch_bounds__(128) void scan_sums_kernel(const int* __restrict__ tileSum,
                                                        int* __restrict__ tileOff,
                                                        int* __restrict__ rowptr) {
    __shared__ int ps[128];
    int tid = threadIdx.x;
    int v = (tid < NTILES) ? tileSum[tid] : 0;
    ps[tid] = v;
    __syncthreads();
    for (int off = 1; off < 128; off <<= 1) {
        int t = (tid >= off) ? ps[tid - off] : 0;
        __syncthreads();
        ps[tid] += t;
        __syncthreads();
    }
    if (tid < NTILES) tileOff[tid] = ps[tid] - v;
    if (tid == 127) rowptr[N_NODES] = ps[127];
}

// ---------------- scan stage 3: finalize rowptr, dinv, zero cursor ----------------
__global__ void finalize_kernel(const int* __restrict__ cnt,
                                const int* __restrict__ tileOff,
                                int* __restrict__ rowptr,
                                float* __restrict__ dinv,
                                int* __restrict__ cursor) {
    int i = blockIdx.x * blockDim.x + threadIdx.x;
    if (i < N_NODES) {
        rowptr[i] += tileOff[i / TILE];
        dinv[i]    = rsqrtf(fmaxf((float)cnt[i], 1.0f));
        cursor[i]  = 0;
    }
}

// ---------------- fill CSR column array ----------------
__global__ void fill_kernel(const int* __restrict__ ei,
                            const int* __restrict__ rowptr,
                            int* __restrict__ cursor,
                            int* __restrict__ csr_col) {
    int e = blockIdx.x * blockDim.x + threadIdx.x;
    if (e < N_EDGES) {
        int r = ei[e];
        int c = ei[N_EDGES + e];
        int pos = rowptr[r] + atomicAdd(&cursor[r], 1);
        csr_col[pos] = c;
    }
}

// ---------------- transpose W [OUTF][HIDDEN] -> Wt [HIDDEN][OUTF] in global ----------------
__global__ void wtrans_kernel(const float* __restrict__ W, float* __restrict__ Wt) {
    int i = blockIdx.x * blockDim.x + threadIdx.x;   // 8192 threads
    if (i < HIDDEN * OUTF) {
        int o = i / HIDDEN, k = i % HIDDEN;
        Wt[k * OUTF + o] = W[i];   // coalesced read; scattered write (tiny, L2)
    }
}

// ---------------- gemm: y0 = x @ W^T  (64 rows/block, 4x4 register tile) ----------------
#define HPAD 132
#define GR   64
__global__ __launch_bounds__(256) void gemm_kernel(const float* __restrict__ x,
                                                   const float* __restrict__ Wt,
                                                   float* __restrict__ y0) {
    __shared__ float wt[HIDDEN * OUTF];   // [k][o] — direct copy of Wt, conflict-free
    __shared__ float hs[GR * HPAD];       // [r][k] padded
    int tid = threadIdx.x;

    for (int i = tid; i < HIDDEN * OUTF; i += 256) wt[i] = Wt[i];
    int rowBase = blockIdx.x * GR;
    for (int i = tid; i < GR * HIDDEN; i += 256) {
        int r = i >> 7, k = i & 127;
        int row = rowBase + r;
        hs[r * HPAD + k] = (row < N_NODES) ? x[(size_t)row * HIDDEN + k] : 0.f;
    }
    __syncthreads();

    int o4 = (tid & 15) * 4;
    int rq = (tid >> 4) * 4;   // 4 consecutive rows per thread
    float4 a0 = {0,0,0,0}, a1 = {0,0,0,0}, a2 = {0,0,0,0}, a3 = {0,0,0,0};
    #pragma unroll 4
    for (int k = 0; k < HIDDEN; ++k) {
        float4 wv = *(const float4*)&wt[k * OUTF + o4];
        float h0 = hs[(rq + 0) * HPAD + k];
        float h1 = hs[(rq + 1) * HPAD + k];
        float h2 = hs[(rq + 2) * HPAD + k];
        float h3 = hs[(rq + 3) * HPAD + k];
        a0.x += h0 * wv.x; a0.y += h0 * wv.y; a0.z += h0 * wv.z; a0.w += h0 * wv.w;
        a1.x += h1 * wv.x; a1.y += h1 * wv.y; a1.z += h1 * wv.z; a1.w += h1 * wv.w;
        a2.x += h2 * wv.x; a2.y += h2 * wv.y; a2.z += h2 * wv.z; a2.w += h2 * wv.w;
        a3.x += h3 * wv.x; a3.y += h3 * wv.y; a3.z += h3 * wv.z; a3.w += h3 * wv.w;
    }
    int row = rowBase + rq;
    if (row + 0 < N_NODES) *(float4*)&y0[(size_t)(row + 0) * OUTF + o4] = a0;
    if (row + 1 < N_NODES) *(float4*)&y0[(size_t)(row + 1) * OUTF + o4] = a1;
    if (row + 2 < N_NODES) *(float4*)&y0[(size_t)(row + 2) * OUTF + o4] = a2;
    if (row + 3 < N_NODES) *(float4*)&y0[(size_t)(row + 3) * OUTF + o4] = a3;
}

// ---------------- pull propagate on 64-wide features: one wave per node ----------------
// ydst[n] = dinv[n] * sum_{c in adj(n)} dinv[c] * ysrc[c]   (each lane = one feature)
__global__ __launch_bounds__(256) void pull_kernel(const int* __restrict__ rowptr,
                                                   const int* __restrict__ csr_col,
                                                   const float* __restrict__ dinv,
                                                   const float* __restrict__ ysrc,
                                                   float* __restrict__ ydst) {
    int node = blockIdx.x * 4 + (threadIdx.x >> 6);
    int lane = threadIdx.x & 63;
    if (node >= N_NODES) return;
    int s = rowptr[node];
    int e = rowptr[node + 1];
    float dr = dinv[node];
    float acc = 0.f;
    int i = s;
    for (; i + 3 < e; i += 4) {
        int c0 = csr_col[i];
        int c1 = csr_col[i + 1];
        int c2 = csr_col[i + 2];
        int c3 = csr_col[i + 3];
        float w0 = dinv[c0], w1 = dinv[c1], w2 = dinv[c2], w3 = dinv[c3];
        float v0 = ysrc[(size_t)c0 * OUTF + lane];
        float v1 = ysrc[(size_t)c1 * OUTF + lane];
        float v2 = ysrc[(size_t)c2 * OUTF + lane];
        float v3 = ysrc[(size_t)c3 * OUTF + lane];
        acc += w0 * v0 + w1 * v1;
        acc += w2 * v2 + w3 * v3;
    }
    for (; i < e; ++i) {
        int c0 = csr_col[i];
        acc += dinv[c0] * ysrc[(size_t)c0 * OUTF + lane];
    }
    ydst[(size_t)node * OUTF + lane] = acc * dr;
}

// ---------------- merge: out = 0.25*(y0+y1+y2+y3) + b ----------------
__global__ void merge_kernel(const float4* __restrict__ y0,
                             const float4* __restrict__ y1,
                             const float4* __restrict__ y2,
                             const float4* __restrict__ y3,
                             const float* __restrict__ b,
                             float4* __restrict__ out) {
    int i = blockIdx.x * blockDim.x + threadIdx.x;   // over N*64/4
    if (i >= N_NODES * OUTF / 4) return;
    int o4 = (i * 4) & (OUTF - 1);
    float4 v0 = y0[i], v1 = y1[i], v2 = y2[i], v3 = y3[i];
    float4 bv = *(const float4*)(b + o4);
    float4 r;
    r.x = 0.25f * (v0.x + v1.x + v2.x + v3.x) + bv.x;
    r.y = 0.25f * (v0.y + v1.y + v2.y + v3.y) + bv.y;
    r.z = 0.25f * (v0.z + v1.z + v2.z + v3.z) + bv.z;
    r.w = 0.25f * (v0.w + v1.w + v2.w + v3.w) + bv.w;
    out[i] = r;
}

extern "C" void kernel_launch(void* const* d_in, const int* in_sizes, int n_in,
                              void* d_out, int out_size, void* d_ws, size_t ws_size,
                              hipStream_t stream) {
    const float* x  = (const float*)d_in[0];
    const int*   ei = (const int*)d_in[1];     // int32, [2, E] flat
    const float* W  = (const float*)d_in[2];
    const float* b  = (const float*)d_in[3];
    float*       out = (float*)d_out;

    // workspace layout (4B elements) — ~110 MB total
    float* y0      = (float*)d_ws;                          // N*64
    float* y1      = y0 + (size_t)N_NODES * OUTF;           // N*64
    float* y2      = y1 + (size_t)N_NODES * OUTF;           // N*64
    float* y3      = y2 + (size_t)N_NODES * OUTF;           // N*64
    float* Wt      = y3 + (size_t)N_NODES * OUTF;           // 8192
    int*   csrcol  = (int*)(Wt + HIDDEN * OUTF);            // E
    int*   rowptr  = csrcol + N_EDGES;                      // N+1
    int*   cnt     = rowptr + (N_NODES + 1);                // N
    float* dinv    = (float*)(cnt + N_NODES);               // N
    int*   tileSum = (int*)(dinv + N_NODES);                // NTILES
    int*   tileOff = tileSum + NTILES;                      // NTILES

    const int BLK = 256;
    const int edgeBlocks  = (N_EDGES + BLK - 1) / BLK;
    const int nodeBlocks  = (N_NODES + BLK - 1) / BLK;
    const int cntZero4    = (N_NODES / 4 + BLK - 1) / BLK;
    const int pullBlocks  = (N_NODES + 3) / 4;
    const int gemmBlocks  = (N_NODES + GR - 1) / GR;        // 1563
    const int mergeBlocks = (N_NODES * OUTF / 4 + BLK - 1) / BLK;

    // ---- CSR build ----
    zero_kernel<<<cntZero4, BLK, 0, stream>>>((int4*)cnt, N_NODES / 4);
    count_kernel<<<edgeBlocks, BLK, 0, stream>>>(ei, cnt);
    scan_tiles_kernel<<<NTILES, BLK, 0, stream>>>(cnt, rowptr, tileSum);
    scan_sums_kernel<<<1, 128, 0, stream>>>(tileSum, tileOff, rowptr);
    finalize_kernel<<<nodeBlocks, BLK, 0, stream>>>(cnt, tileOff, rowptr, dinv, cnt);
    fill_kernel<<<edgeBlocks, BLK, 0, stream>>>(ei, rowptr, cnt, csrcol);

    // ---- project once, then propagate in 64-dim ----
    wtrans_kernel<<<(HIDDEN * OUTF + BLK - 1) / BLK, BLK, 0, stream>>>(W, Wt);
    gemm_kernel<<<gemmBlocks, BLK, 0, stream>>>(x, Wt, y0);
    pull_kernel<<<pullBlocks, BLK, 0, stream>>>(rowptr, csrcol, dinv, y0, y1);
    pull_kernel<<<pullBlocks, BLK, 0, stream>>>(rowptr, csrcol, dinv, y1, y2);
    pull_kernel<<<pullBlocks, BLK, 0, stream>>>(rowptr, csrcol, dinv, y2, y3);
    merge_kernel<<<mergeBlocks, BLK, 0, stream>>>((const float4*)y0, (const float4*)y1,
                                                  (const float4*)y2, (const float4*)y3,
                                                  b, (float4*)out);
}

// Round 6
// 487.937 us; speedup vs baseline: 17.8601x; 1.1058x over previous
//
#include <hip/hip_runtime.h>

#define N_NODES 100000
#define N_EDGES 1600000
#define HIDDEN  128
#define OUTF    64
#define TILE    1024
#define NTILES  ((N_NODES + TILE - 1) / TILE)   // 98

// ---------------- zero ints ----------------
__global__ void zero_kernel(int4* p, int n4) {
    int i = blockIdx.x * blockDim.x + threadIdx.x;
    if (i < n4) p[i] = make_int4(0, 0, 0, 0);
}

// ---------------- count destination degrees (int atomics) ----------------
__global__ void count_kernel(const int* __restrict__ ei, int* __restrict__ cnt) {
    int e = blockIdx.x * blockDim.x + threadIdx.x;
    if (e < N_EDGES) atomicAdd(&cnt[ei[e]], 1);
}

// ---------------- scan stage 1: per-tile exclusive scan ----------------
__global__ __launch_bounds__(256) void scan_tiles_kernel(const int* __restrict__ cnt,
                                                         int* __restrict__ rowptr,
                                                         int* __restrict__ tileSum) {
    __shared__ int ps[256];
    int tid  = threadIdx.x;
    int base = blockIdx.x * TILE + tid * 4;
    int a0 = 0, a1 = 0, a2 = 0, a3 = 0;
    if (base + 3 < N_NODES) {
        int4 v = *(const int4*)(cnt + base);
        a0 = v.x; a1 = v.y; a2 = v.z; a3 = v.w;
    } else {
        if (base + 0 < N_NODES) a0 = cnt[base + 0];
        if (base + 1 < N_NODES) a1 = cnt[base + 1];
        if (base + 2 < N_NODES) a2 = cnt[base + 2];
        if (base + 3 < N_NODES) a3 = cnt[base + 3];
    }
    int s = a0 + a1 + a2 + a3;
    ps[tid] = s;
    __syncthreads();
    for (int off = 1; off < 256; off <<= 1) {
        int t = (tid >= off) ? ps[tid - off] : 0;
        __syncthreads();
        ps[tid] += t;
        __syncthreads();
    }
    int ex = ps[tid] - s;
    int e0 = ex, e1 = e0 + a0, e2 = e1 + a1, e3 = e2 + a2;
    if (base + 3 < N_NODES) {
        *(int4*)(rowptr + base) = make_int4(e0, e1, e2, e3);
    } else {
        if (base + 0 < N_NODES) rowptr[base + 0] = e0;
        if (base + 1 < N_NODES) rowptr[base + 1] = e1;
        if (base + 2 < N_NODES) rowptr[base + 2] = e2;
        if (base + 3 < N_NODES) rowptr[base + 3] = e3;
    }
    if (tid == 255) tileSum[blockIdx.x] = ps[255];
}

// ---------------- scan stage 2: scan tile sums ----------------
__global__ __launch_bounds__(128) void scan_sums_kernel(const int* __restrict__ tileSum,
                                                        int* __restrict__ tileOff,
                                                        int* __restrict__ rowptr) {
    __shared__ int ps[128];
    int tid = threadIdx.x;
    int v = (tid < NTILES) ? tileSum[tid] : 0;
    ps[tid] = v;
    __syncthreads();
    for (int off = 1; off < 128; off <<= 1) {
        int t = (tid >= off) ? ps[tid - off] : 0;
        __syncthreads();
        ps[tid] += t;
        __syncthreads();
    }
    if (tid < NTILES) tileOff[tid] = ps[tid] - v;
    if (tid == 127) rowptr[N_NODES] = ps[127];
}

// ---------------- scan stage 3: finalize rowptr, dinv, zero cursor ----------------
__global__ void finalize_kernel(const int* __restrict__ cnt,
                                const int* __restrict__ tileOff,
                                int* __restrict__ rowptr,
                                float* __restrict__ dinv,
                                int* __restrict__ cursor) {
    int i = blockIdx.x * blockDim.x + threadIdx.x;
    if (i < N_NODES) {
        rowptr[i] += tileOff[i / TILE];
        dinv[i]    = rsqrtf(fmaxf((float)cnt[i], 1.0f));
        cursor[i]  = 0;
    }
}

// ---------------- fill CSR column array ----------------
__global__ void fill_kernel(const int* __restrict__ ei,
                            const int* __restrict__ rowptr,
                            int* __restrict__ cursor,
                            int* __restrict__ csr_col) {
    int e = blockIdx.x * blockDim.x + threadIdx.x;
    if (e < N_EDGES) {
        int r = ei[e];
        int c = ei[N_EDGES + e];
        int pos = rowptr[r] + atomicAdd(&cursor[r], 1);
        csr_col[pos] = c;
    }
}

// ---------------- transpose W [OUTF][HIDDEN] -> Wt [HIDDEN][OUTF] in global ----------------
__global__ void wtrans_kernel(const float* __restrict__ W, float* __restrict__ Wt) {
    int i = blockIdx.x * blockDim.x + threadIdx.x;
    if (i < HIDDEN * OUTF) {
        int o = i / HIDDEN, k = i % HIDDEN;
        Wt[k * OUTF + o] = W[i];
    }
}

// ---------------- gemm: y0 = x @ W^T  (64x64 tile, K staged in 4 chunks of 32) ----------------
// LDS ~18KB -> LDS permits 8 blocks/CU (VGPR caps ~5) vs 2 with full-K staging.
#define GR    64
#define BK    32
#define HSP   36   // hs row stride (pad 4)
#define WTP   68   // wt row stride (pad 4)
__global__ __launch_bounds__(256) void gemm_kernel(const float* __restrict__ x,
                                                   const float* __restrict__ Wt,
                                                   float* __restrict__ y0) {
    __shared__ float hs[GR * HSP];   // [row][kk]
    __shared__ float wt[BK * WTP];   // [kk][o]
    int tid = threadIdx.x;
    int rowBase = blockIdx.x * GR;

    int o4 = (tid & 15) * 4;
    int rq = (tid >> 4) * 4;
    float4 a0 = {0,0,0,0}, a1 = {0,0,0,0}, a2 = {0,0,0,0}, a3 = {0,0,0,0};

    for (int kt = 0; kt < HIDDEN / BK; ++kt) {
        if (kt) __syncthreads();
        int kbase = kt * BK;
        // stage hs: 64 rows x 32 k = 512 float4, 2 per thread
        #pragma unroll
        for (int t = 0; t < 2; ++t) {
            int f = tid + t * 256;
            int r = f >> 3, c4 = (f & 7) * 4;
            int row = rowBase + r;
            float4 v = (row < N_NODES) ? *(const float4*)(x + (size_t)row * HIDDEN + kbase + c4)
                                       : make_float4(0.f, 0.f, 0.f, 0.f);
            *(float4*)&hs[r * HSP + c4] = v;
        }
        // stage wt: 32 k x 64 o = 512 float4, 2 per thread
        #pragma unroll
        for (int t = 0; t < 2; ++t) {
            int f = tid + t * 256;
            int k = f >> 4, c4 = (f & 15) * 4;
            float4 v = *(const float4*)(Wt + (size_t)(kbase + k) * OUTF + c4);
            *(float4*)&wt[k * WTP + c4] = v;
        }
        __syncthreads();
        #pragma unroll 8
        for (int kk = 0; kk < BK; ++kk) {
            float4 wv = *(const float4*)&wt[kk * WTP + o4];
            float h0 = hs[(rq + 0) * HSP + kk];
            float h1 = hs[(rq + 1) * HSP + kk];
            float h2 = hs[(rq + 2) * HSP + kk];
            float h3 = hs[(rq + 3) * HSP + kk];
            a0.x += h0 * wv.x; a0.y += h0 * wv.y; a0.z += h0 * wv.z; a0.w += h0 * wv.w;
            a1.x += h1 * wv.x; a1.y += h1 * wv.y; a1.z += h1 * wv.z; a1.w += h1 * wv.w;
            a2.x += h2 * wv.x; a2.y += h2 * wv.y; a2.z += h2 * wv.z; a2.w += h2 * wv.w;
            a3.x += h3 * wv.x; a3.y += h3 * wv.y; a3.z += h3 * wv.z; a3.w += h3 * wv.w;
        }
    }
    int row = rowBase + rq;
    if (row + 0 < N_NODES) *(float4*)&y0[(size_t)(row + 0) * OUTF + o4] = a0;
    if (row + 1 < N_NODES) *(float4*)&y0[(size_t)(row + 1) * OUTF + o4] = a1;
    if (row + 2 < N_NODES) *(float4*)&y0[(size_t)(row + 2) * OUTF + o4] = a2;
    if (row + 3 < N_NODES) *(float4*)&y0[(size_t)(row + 3) * OUTF + o4] = a3;
}

// ---------------- pull propagate on 64-wide features: one wave per node ----------------
__global__ __launch_bounds__(256) void pull_kernel(const int* __restrict__ rowptr,
                                                   const int* __restrict__ csr_col,
                                                   const float* __restrict__ dinv,
                                                   const float* __restrict__ ysrc,
                                                   float* __restrict__ ydst) {
    int node = blockIdx.x * 4 + (threadIdx.x >> 6);
    int lane = threadIdx.x & 63;
    if (node >= N_NODES) return;
    int s = rowptr[node];
    int e = rowptr[node + 1];
    float dr = dinv[node];
    float acc = 0.f;
    int i = s;
    for (; i + 3 < e; i += 4) {
        int c0 = csr_col[i];
        int c1 = csr_col[i + 1];
        int c2 = csr_col[i + 2];
        int c3 = csr_col[i + 3];
        float w0 = dinv[c0], w1 = dinv[c1], w2 = dinv[c2], w3 = dinv[c3];
        float v0 = ysrc[(size_t)c0 * OUTF + lane];
        float v1 = ysrc[(size_t)c1 * OUTF + lane];
        float v2 = ysrc[(size_t)c2 * OUTF + lane];
        float v3 = ysrc[(size_t)c3 * OUTF + lane];
        acc += w0 * v0 + w1 * v1;
        acc += w2 * v2 + w3 * v3;
    }
    for (; i < e; ++i) {
        int c0 = csr_col[i];
        acc += dinv[c0] * ysrc[(size_t)c0 * OUTF + lane];
    }
    ydst[(size_t)node * OUTF + lane] = acc * dr;
}

// ---------------- fused layer-3 pull + mean + bias: out = 0.25*(y0+y1+y2+pull(y2)) + b ----------------
__global__ __launch_bounds__(256) void pull_merge_kernel(const int* __restrict__ rowptr,
                                                         const int* __restrict__ csr_col,
                                                         const float* __restrict__ dinv,
                                                         const float* __restrict__ y0,
                                                         const float* __restrict__ y1,
                                                         const float* __restrict__ y2,
                                                         const float* __restrict__ b,
                                                         float* __restrict__ out) {
    int node = blockIdx.x * 4 + (threadIdx.x >> 6);
    int lane = threadIdx.x & 63;
    if (node >= N_NODES) return;
    int s = rowptr[node];
    int e = rowptr[node + 1];
    float dr = dinv[node];
    float acc = 0.f;
    int i = s;
    for (; i + 3 < e; i += 4) {
        int c0 = csr_col[i];
        int c1 = csr_col[i + 1];
        int c2 = csr_col[i + 2];
        int c3 = csr_col[i + 3];
        float w0 = dinv[c0], w1 = dinv[c1], w2 = dinv[c2], w3 = dinv[c3];
        float v0 = y2[(size_t)c0 * OUTF + lane];
        float v1 = y2[(size_t)c1 * OUTF + lane];
        float v2 = y2[(size_t)c2 * OUTF + lane];
        float v3 = y2[(size_t)c3 * OUTF + lane];
        acc += w0 * v0 + w1 * v1;
        acc += w2 * v2 + w3 * v3;
    }
    for (; i < e; ++i) {
        int c0 = csr_col[i];
        acc += dinv[c0] * y2[(size_t)c0 * OUTF + lane];
    }
    size_t idx = (size_t)node * OUTF + lane;
    float sum = y0[idx] + y1[idx] + y2[idx] + acc * dr;
    out[idx] = 0.25f * sum + b[lane];
}

extern "C" void kernel_launch(void* const* d_in, const int* in_sizes, int n_in,
                              void* d_out, int out_size, void* d_ws, size_t ws_size,
                              hipStream_t stream) {
    const float* x  = (const float*)d_in[0];
    const int*   ei = (const int*)d_in[1];     // int32, [2, E] flat
    const float* W  = (const float*)d_in[2];
    const float* b  = (const float*)d_in[3];
    float*       out = (float*)d_out;

    // workspace layout (4B elements)
    float* y0      = (float*)d_ws;                          // N*64
    float* y1      = y0 + (size_t)N_NODES * OUTF;           // N*64
    float* y2      = y1 + (size_t)N_NODES * OUTF;           // N*64
    float* Wt      = y2 + (size_t)N_NODES * OUTF;           // 8192
    int*   csrcol  = (int*)(Wt + HIDDEN * OUTF);            // E
    int*   rowptr  = csrcol + N_EDGES;                      // N+1
    int*   cnt     = rowptr + (N_NODES + 1);                // N
    float* dinv    = (float*)(cnt + N_NODES);               // N
    int*   tileSum = (int*)(dinv + N_NODES);                // NTILES
    int*   tileOff = tileSum + NTILES;                      // NTILES

    const int BLK = 256;
    const int edgeBlocks  = (N_EDGES + BLK - 1) / BLK;
    const int nodeBlocks  = (N_NODES + BLK - 1) / BLK;
    const int cntZero4    = (N_NODES / 4 + BLK - 1) / BLK;
    const int pullBlocks  = (N_NODES + 3) / 4;
    const int gemmBlocks  = (N_NODES + GR - 1) / GR;        // 1563

    // ---- CSR build ----
    zero_kernel<<<cntZero4, BLK, 0, stream>>>((int4*)cnt, N_NODES / 4);
    count_kernel<<<edgeBlocks, BLK, 0, stream>>>(ei, cnt);
    scan_tiles_kernel<<<NTILES, BLK, 0, stream>>>(cnt, rowptr, tileSum);
    scan_sums_kernel<<<1, 128, 0, stream>>>(tileSum, tileOff, rowptr);
    finalize_kernel<<<nodeBlocks, BLK, 0, stream>>>(cnt, tileOff, rowptr, dinv, cnt);
    fill_kernel<<<edgeBlocks, BLK, 0, stream>>>(ei, rowptr, cnt, csrcol);

    // ---- project once, propagate in 64-dim, fuse final layer with merge ----
    wtrans_kernel<<<(HIDDEN * OUTF + BLK - 1) / BLK, BLK, 0, stream>>>(W, Wt);
    gemm_kernel<<<gemmBlocks, BLK, 0, stream>>>(x, Wt, y0);
    pull_kernel<<<pullBlocks, BLK, 0, stream>>>(rowptr, csrcol, dinv, y0, y1);
    pull_kernel<<<pullBlocks, BLK, 0, stream>>>(rowptr, csrcol, dinv, y1, y2);
    pull_merge_kernel<<<pullBlocks, BLK, 0, stream>>>(rowptr, csrcol, dinv, y0, y1, y2, b, out);
}

// Round 7
// 441.124 us; speedup vs baseline: 19.7555x; 1.1061x over previous
//
#include <hip/hip_runtime.h>

#define N_NODES 100000
#define N_EDGES 1600000
#define HIDDEN  128
#define OUTF    64
#define TILE    1024
#define NTILES  ((N_NODES + TILE - 1) / TILE)   // 98

// ---------------- zero ints ----------------
__global__ void zero_kernel(int4* p, int n4) {
    int i = blockIdx.x * blockDim.x + threadIdx.x;
    if (i < n4) p[i] = make_int4(0, 0, 0, 0);
}

// ---------------- count degrees; atomic return value IS the intra-row rank ----------------
__global__ void count_kernel(const int* __restrict__ ei,
                             int* __restrict__ cnt,
                             int* __restrict__ rank) {
    int t  = blockIdx.x * blockDim.x + threadIdx.x;
    int e0 = t * 4;
    if (e0 + 3 < N_EDGES) {
        int4 r4 = *(const int4*)(ei + e0);
        int k0 = atomicAdd(&cnt[r4.x], 1);
        int k1 = atomicAdd(&cnt[r4.y], 1);
        int k2 = atomicAdd(&cnt[r4.z], 1);
        int k3 = atomicAdd(&cnt[r4.w], 1);
        *(int4*)(rank + e0) = make_int4(k0, k1, k2, k3);
    } else {
        for (int e = e0; e < N_EDGES; ++e) rank[e] = atomicAdd(&cnt[ei[e]], 1);
    }
}

// ---------------- scan stage 1: per-tile exclusive scan ----------------
__global__ __launch_bounds__(256) void scan_tiles_kernel(const int* __restrict__ cnt,
                                                         int* __restrict__ rowptr,
                                                         int* __restrict__ tileSum) {
    __shared__ int ps[256];
    int tid  = threadIdx.x;
    int base = blockIdx.x * TILE + tid * 4;
    int a0 = 0, a1 = 0, a2 = 0, a3 = 0;
    if (base + 3 < N_NODES) {
        int4 v = *(const int4*)(cnt + base);
        a0 = v.x; a1 = v.y; a2 = v.z; a3 = v.w;
    } else {
        if (base + 0 < N_NODES) a0 = cnt[base + 0];
        if (base + 1 < N_NODES) a1 = cnt[base + 1];
        if (base + 2 < N_NODES) a2 = cnt[base + 2];
        if (base + 3 < N_NODES) a3 = cnt[base + 3];
    }
    int s = a0 + a1 + a2 + a3;
    ps[tid] = s;
    __syncthreads();
    for (int off = 1; off < 256; off <<= 1) {
        int t = (tid >= off) ? ps[tid - off] : 0;
        __syncthreads();
        ps[tid] += t;
        __syncthreads();
    }
    int ex = ps[tid] - s;
    int e0 = ex, e1 = e0 + a0, e2 = e1 + a1, e3 = e2 + a2;
    if (base + 3 < N_NODES) {
        *(int4*)(rowptr + base) = make_int4(e0, e1, e2, e3);
    } else {
        if (base + 0 < N_NODES) rowptr[base + 0] = e0;
        if (base + 1 < N_NODES) rowptr[base + 1] = e1;
        if (base + 2 < N_NODES) rowptr[base + 2] = e2;
        if (base + 3 < N_NODES) rowptr[base + 3] = e3;
    }
    if (tid == 255) tileSum[blockIdx.x] = ps[255];
}

// ---------------- scan stage 2: scan tile sums ----------------
__global__ __launch_bounds__(128) void scan_sums_kernel(const int* __restrict__ tileSum,
                                                        int* __restrict__ tileOff,
                                                        int* __restrict__ rowptr) {
    __shared__ int ps[128];
    int tid = threadIdx.x;
    int v = (tid < NTILES) ? tileSum[tid] : 0;
    ps[tid] = v;
    __syncthreads();
    for (int off = 1; off < 128; off <<= 1) {
        int t = (tid >= off) ? ps[tid - off] : 0;
        __syncthreads();
        ps[tid] += t;
        __syncthreads();
    }
    if (tid < NTILES) tileOff[tid] = ps[tid] - v;
    if (tid == 127) rowptr[N_NODES] = ps[127];
}

// ---------------- scan stage 3: finalize rowptr, dinv ----------------
__global__ void finalize_kernel(const int* __restrict__ cnt,
                                const int* __restrict__ tileOff,
                                int* __restrict__ rowptr,
                                float* __restrict__ dinv) {
    int i = blockIdx.x * blockDim.x + threadIdx.x;
    if (i < N_NODES) {
        rowptr[i] += tileOff[i / TILE];
        dinv[i]    = rsqrtf(fmaxf((float)cnt[i], 1.0f));
    }
}

// ---------------- fill CSR columns: NO atomics, 4-edge ILP ----------------
__global__ void fill_kernel(const int* __restrict__ ei,
                            const int* __restrict__ rowptr,
                            const int* __restrict__ rank,
                            int* __restrict__ csr_col) {
    int t  = blockIdx.x * blockDim.x + threadIdx.x;
    int e0 = t * 4;
    if (e0 + 3 < N_EDGES) {
        int4 r4 = *(const int4*)(ei + e0);
        int4 c4 = *(const int4*)(ei + N_EDGES + e0);
        int4 k4 = *(const int4*)(rank + e0);
        int p0 = rowptr[r4.x] + k4.x;
        int p1 = rowptr[r4.y] + k4.y;
        int p2 = rowptr[r4.z] + k4.z;
        int p3 = rowptr[r4.w] + k4.w;
        csr_col[p0] = c4.x;
        csr_col[p1] = c4.y;
        csr_col[p2] = c4.z;
        csr_col[p3] = c4.w;
    } else {
        for (int e = e0; e < N_EDGES; ++e)
            csr_col[rowptr[ei[e]] + rank[e]] = ei[N_EDGES + e];
    }
}

// ---------------- transpose W [OUTF][HIDDEN] -> Wt [HIDDEN][OUTF] in global ----------------
__global__ void wtrans_kernel(const float* __restrict__ W, float* __restrict__ Wt) {
    int i = blockIdx.x * blockDim.x + threadIdx.x;
    if (i < HIDDEN * OUTF) {
        int o = i / HIDDEN, k = i % HIDDEN;
        Wt[k * OUTF + o] = W[i];
    }
}

// ---------------- gemm: y0 = x @ W^T  (64x64 tile, K staged in 4 chunks of 32) ----------------
#define GR    64
#define BK    32
#define HSP   36   // hs row stride (pad 4)
#define WTP   68   // wt row stride (pad 4)
__global__ __launch_bounds__(256) void gemm_kernel(const float* __restrict__ x,
                                                   const float* __restrict__ Wt,
                                                   float* __restrict__ y0) {
    __shared__ float hs[GR * HSP];   // [row][kk]
    __shared__ float wt[BK * WTP];   // [kk][o]
    int tid = threadIdx.x;
    int rowBase = blockIdx.x * GR;

    int o4 = (tid & 15) * 4;
    int rq = (tid >> 4) * 4;
    float4 a0 = {0,0,0,0}, a1 = {0,0,0,0}, a2 = {0,0,0,0}, a3 = {0,0,0,0};

    for (int kt = 0; kt < HIDDEN / BK; ++kt) {
        if (kt) __syncthreads();
        int kbase = kt * BK;
        #pragma unroll
        for (int t = 0; t < 2; ++t) {
            int f = tid + t * 256;
            int r = f >> 3, c4 = (f & 7) * 4;
            int row = rowBase + r;
            float4 v = (row < N_NODES) ? *(const float4*)(x + (size_t)row * HIDDEN + kbase + c4)
                                       : make_float4(0.f, 0.f, 0.f, 0.f);
            *(float4*)&hs[r * HSP + c4] = v;
        }
        #pragma unroll
        for (int t = 0; t < 2; ++t) {
            int f = tid + t * 256;
            int k = f >> 4, c4 = (f & 15) * 4;
            float4 v = *(const float4*)(Wt + (size_t)(kbase + k) * OUTF + c4);
            *(float4*)&wt[k * WTP + c4] = v;
        }
        __syncthreads();
        #pragma unroll 8
        for (int kk = 0; kk < BK; ++kk) {
            float4 wv = *(const float4*)&wt[kk * WTP + o4];
            float h0 = hs[(rq + 0) * HSP + kk];
            float h1 = hs[(rq + 1) * HSP + kk];
            float h2 = hs[(rq + 2) * HSP + kk];
            float h3 = hs[(rq + 3) * HSP + kk];
            a0.x += h0 * wv.x; a0.y += h0 * wv.y; a0.z += h0 * wv.z; a0.w += h0 * wv.w;
            a1.x += h1 * wv.x; a1.y += h1 * wv.y; a1.z += h1 * wv.z; a1.w += h1 * wv.w;
            a2.x += h2 * wv.x; a2.y += h2 * wv.y; a2.z += h2 * wv.z; a2.w += h2 * wv.w;
            a3.x += h3 * wv.x; a3.y += h3 * wv.y; a3.z += h3 * wv.z; a3.w += h3 * wv.w;
        }
    }
    int row = rowBase + rq;
    if (row + 0 < N_NODES) *(float4*)&y0[(size_t)(row + 0) * OUTF + o4] = a0;
    if (row + 1 < N_NODES) *(float4*)&y0[(size_t)(row + 1) * OUTF + o4] = a1;
    if (row + 2 < N_NODES) *(float4*)&y0[(size_t)(row + 2) * OUTF + o4] = a2;
    if (row + 3 < N_NODES) *(float4*)&y0[(size_t)(row + 3) * OUTF + o4] = a3;
}

// ---------------- pull propagate on 64-wide features: one wave per node ----------------
__global__ __launch_bounds__(256) void pull_kernel(const int* __restrict__ rowptr,
                                                   const int* __restrict__ csr_col,
                                                   const float* __restrict__ dinv,
                                                   const float* __restrict__ ysrc,
                                                   float* __restrict__ ydst) {
    int node = blockIdx.x * 4 + (threadIdx.x >> 6);
    int lane = threadIdx.x & 63;
    if (node >= N_NODES) return;
    int s = rowptr[node];
    int e = rowptr[node + 1];
    float dr = dinv[node];
    float acc = 0.f;
    int i = s;
    for (; i + 3 < e; i += 4) {
        int c0 = csr_col[i];
        int c1 = csr_col[i + 1];
        int c2 = csr_col[i + 2];
        int c3 = csr_col[i + 3];
        float w0 = dinv[c0], w1 = dinv[c1], w2 = dinv[c2], w3 = dinv[c3];
        float v0 = ysrc[(size_t)c0 * OUTF + lane];
        float v1 = ysrc[(size_t)c1 * OUTF + lane];
        float v2 = ysrc[(size_t)c2 * OUTF + lane];
        float v3 = ysrc[(size_t)c3 * OUTF + lane];
        acc += w0 * v0 + w1 * v1;
        acc += w2 * v2 + w3 * v3;
    }
    for (; i < e; ++i) {
        int c0 = csr_col[i];
        acc += dinv[c0] * ysrc[(size_t)c0 * OUTF + lane];
    }
    ydst[(size_t)node * OUTF + lane] = acc * dr;
}

// ---------------- fused layer-3 pull + mean + bias ----------------
__global__ __launch_bounds__(256) void pull_merge_kernel(const int* __restrict__ rowptr,
                                                         const int* __restrict__ csr_col,
                                                         const float* __restrict__ dinv,
                                                         const float* __restrict__ y0,
                                                         const float* __restrict__ y1,
                                                         const float* __restrict__ y2,
                                                         const float* __restrict__ b,
                                                         float* __restrict__ out) {
    int node = blockIdx.x * 4 + (threadIdx.x >> 6);
    int lane = threadIdx.x & 63;
    if (node >= N_NODES) return;
    int s = rowptr[node];
    int e = rowptr[node + 1];
    float dr = dinv[node];
    float acc = 0.f;
    int i = s;
    for (; i + 3 < e; i += 4) {
        int c0 = csr_col[i];
        int c1 = csr_col[i + 1];
        int c2 = csr_col[i + 2];
        int c3 = csr_col[i + 3];
        float w0 = dinv[c0], w1 = dinv[c1], w2 = dinv[c2], w3 = dinv[c3];
        float v0 = y2[(size_t)c0 * OUTF + lane];
        float v1 = y2[(size_t)c1 * OUTF + lane];
        float v2 = y2[(size_t)c2 * OUTF + lane];
        float v3 = y2[(size_t)c3 * OUTF + lane];
        acc += w0 * v0 + w1 * v1;
        acc += w2 * v2 + w3 * v3;
    }
    for (; i < e; ++i) {
        int c0 = csr_col[i];
        acc += dinv[c0] * y2[(size_t)c0 * OUTF + lane];
    }
    size_t idx = (size_t)node * OUTF + lane;
    float sum = y0[idx] + y1[idx] + y2[idx] + acc * dr;
    out[idx] = 0.25f * sum + b[lane];
}

extern "C" void kernel_launch(void* const* d_in, const int* in_sizes, int n_in,
                              void* d_out, int out_size, void* d_ws, size_t ws_size,
                              hipStream_t stream) {
    const float* x  = (const float*)d_in[0];
    const int*   ei = (const int*)d_in[1];     // int32, [2, E] flat
    const float* W  = (const float*)d_in[2];
    const float* b  = (const float*)d_in[3];
    float*       out = (float*)d_out;

    // workspace layout (4B elements)
    float* y0      = (float*)d_ws;                          // N*64
    float* y1      = y0 + (size_t)N_NODES * OUTF;           // N*64
    float* y2      = y1 + (size_t)N_NODES * OUTF;           // N*64
    float* Wt      = y2 + (size_t)N_NODES * OUTF;           // 8192
    int*   csrcol  = (int*)(Wt + HIDDEN * OUTF);            // E
    int*   rank    = csrcol + N_EDGES;                      // E
    int*   rowptr  = rank + N_EDGES;                        // N+1
    int*   cnt     = rowptr + (N_NODES + 1);                // N
    float* dinv    = (float*)(cnt + N_NODES);               // N
    int*   tileSum = (int*)(dinv + N_NODES);                // NTILES
    int*   tileOff = tileSum + NTILES;                      // NTILES

    const int BLK = 256;
    const int edge4Blocks = (N_EDGES / 4 + BLK - 1) / BLK;  // 1563
    const int nodeBlocks  = (N_NODES + BLK - 1) / BLK;
    const int cntZero4    = (N_NODES / 4 + BLK - 1) / BLK;
    const int pullBlocks  = (N_NODES + 3) / 4;
    const int gemmBlocks  = (N_NODES + GR - 1) / GR;        // 1563

    // ---- CSR build ----
    zero_kernel<<<cntZero4, BLK, 0, stream>>>((int4*)cnt, N_NODES / 4);
    count_kernel<<<edge4Blocks, BLK, 0, stream>>>(ei, cnt, rank);
    scan_tiles_kernel<<<NTILES, BLK, 0, stream>>>(cnt, rowptr, tileSum);
    scan_sums_kernel<<<1, 128, 0, stream>>>(tileSum, tileOff, rowptr);
    finalize_kernel<<<nodeBlocks, BLK, 0, stream>>>(cnt, tileOff, rowptr, dinv);
    fill_kernel<<<edge4Blocks, BLK, 0, stream>>>(ei, rowptr, rank, csrcol);

    // ---- project once, propagate in 64-dim, fuse final layer with merge ----
    wtrans_kernel<<<(HIDDEN * OUTF + BLK - 1) / BLK, BLK, 0, stream>>>(W, Wt);
    gemm_kernel<<<gemmBlocks, BLK, 0, stream>>>(x, Wt, y0);
    pull_kernel<<<pullBlocks, BLK, 0, stream>>>(rowptr, csrcol, dinv, y0, y1);
    pull_kernel<<<pullBlocks, BLK, 0, stream>>>(rowptr, csrcol, dinv, y1, y2);
    pull_merge_kernel<<<pullBlocks, BLK, 0, stream>>>(rowptr, csrcol, dinv, y0, y1, y2, b, out);
}

// Round 8
// 413.943 us; speedup vs baseline: 21.0527x; 1.0657x over previous
//
#include <hip/hip_runtime.h>

#define N_NODES 100000
#define N_EDGES 1600000
#define HIDDEN  128
#define OUTF    64
#define TILE    1024
#define NTILES  ((N_NODES + TILE - 1) / TILE)   // 98

// ---------------- bf16 helpers (RTE) ----------------
__device__ __forceinline__ unsigned short f2bf(float f) {
    unsigned u = __float_as_uint(f);
    u += 0x7fffu + ((u >> 16) & 1u);
    return (unsigned short)(u >> 16);
}
__device__ __forceinline__ float bf2f(unsigned short h) {
    return __uint_as_float(((unsigned)h) << 16);
}

// ---------------- zero ints ----------------
__global__ void zero_kernel(int4* p, int n4) {
    int i = blockIdx.x * blockDim.x + threadIdx.x;
    if (i < n4) p[i] = make_int4(0, 0, 0, 0);
}

// ---------------- count degrees; atomic return value IS the intra-row rank ----------------
__global__ void count_kernel(const int* __restrict__ ei,
                             int* __restrict__ cnt,
                             int* __restrict__ rank) {
    int t  = blockIdx.x * blockDim.x + threadIdx.x;
    int e0 = t * 4;
    if (e0 + 3 < N_EDGES) {
        int4 r4 = *(const int4*)(ei + e0);
        int k0 = atomicAdd(&cnt[r4.x], 1);
        int k1 = atomicAdd(&cnt[r4.y], 1);
        int k2 = atomicAdd(&cnt[r4.z], 1);
        int k3 = atomicAdd(&cnt[r4.w], 1);
        *(int4*)(rank + e0) = make_int4(k0, k1, k2, k3);
    } else {
        for (int e = e0; e < N_EDGES; ++e) rank[e] = atomicAdd(&cnt[ei[e]], 1);
    }
}

// ---------------- scan stage 1: per-tile exclusive scan ----------------
__global__ __launch_bounds__(256) void scan_tiles_kernel(const int* __restrict__ cnt,
                                                         int* __restrict__ rowptr,
                                                         int* __restrict__ tileSum) {
    __shared__ int ps[256];
    int tid  = threadIdx.x;
    int base = blockIdx.x * TILE + tid * 4;
    int a0 = 0, a1 = 0, a2 = 0, a3 = 0;
    if (base + 3 < N_NODES) {
        int4 v = *(const int4*)(cnt + base);
        a0 = v.x; a1 = v.y; a2 = v.z; a3 = v.w;
    } else {
        if (base + 0 < N_NODES) a0 = cnt[base + 0];
        if (base + 1 < N_NODES) a1 = cnt[base + 1];
        if (base + 2 < N_NODES) a2 = cnt[base + 2];
        if (base + 3 < N_NODES) a3 = cnt[base + 3];
    }
    int s = a0 + a1 + a2 + a3;
    ps[tid] = s;
    __syncthreads();
    for (int off = 1; off < 256; off <<= 1) {
        int t = (tid >= off) ? ps[tid - off] : 0;
        __syncthreads();
        ps[tid] += t;
        __syncthreads();
    }
    int ex = ps[tid] - s;
    int e0 = ex, e1 = e0 + a0, e2 = e1 + a1, e3 = e2 + a2;
    if (base + 3 < N_NODES) {
        *(int4*)(rowptr + base) = make_int4(e0, e1, e2, e3);
    } else {
        if (base + 0 < N_NODES) rowptr[base + 0] = e0;
        if (base + 1 < N_NODES) rowptr[base + 1] = e1;
        if (base + 2 < N_NODES) rowptr[base + 2] = e2;
        if (base + 3 < N_NODES) rowptr[base + 3] = e3;
    }
    if (tid == 255) tileSum[blockIdx.x] = ps[255];
}

// ---------------- scan stage 2: scan tile sums ----------------
__global__ __launch_bounds__(128) void scan_sums_kernel(const int* __restrict__ tileSum,
                                                        int* __restrict__ tileOff,
                                                        int* __restrict__ rowptr) {
    __shared__ int ps[128];
    int tid = threadIdx.x;
    int v = (tid < NTILES) ? tileSum[tid] : 0;
    ps[tid] = v;
    __syncthreads();
    for (int off = 1; off < 128; off <<= 1) {
        int t = (tid >= off) ? ps[tid - off] : 0;
        __syncthreads();
        ps[tid] += t;
        __syncthreads();
    }
    if (tid < NTILES) tileOff[tid] = ps[tid] - v;
    if (tid == 127) rowptr[N_NODES] = ps[127];
}

// ---------------- scan stage 3: finalize rowptr, dinv ----------------
__global__ void finalize_kernel(const int* __restrict__ cnt,
                                const int* __restrict__ tileOff,
                                int* __restrict__ rowptr,
                                float* __restrict__ dinv) {
    int i = blockIdx.x * blockDim.x + threadIdx.x;
    if (i < N_NODES) {
        rowptr[i] += tileOff[i / TILE];
        dinv[i]    = rsqrtf(fmaxf((float)cnt[i], 1.0f));
    }
}

// ---------------- fill CSR columns: no atomics, 4-edge ILP ----------------
__global__ void fill_kernel(const int* __restrict__ ei,
                            const int* __restrict__ rowptr,
                            const int* __restrict__ rank,
                            int* __restrict__ csr_col) {
    int t  = blockIdx.x * blockDim.x + threadIdx.x;
    int e0 = t * 4;
    if (e0 + 3 < N_EDGES) {
        int4 r4 = *(const int4*)(ei + e0);
        int4 c4 = *(const int4*)(ei + N_EDGES + e0);
        int4 k4 = *(const int4*)(rank + e0);
        int p0 = rowptr[r4.x] + k4.x;
        int p1 = rowptr[r4.y] + k4.y;
        int p2 = rowptr[r4.z] + k4.z;
        int p3 = rowptr[r4.w] + k4.w;
        csr_col[p0] = c4.x;
        csr_col[p1] = c4.y;
        csr_col[p2] = c4.z;
        csr_col[p3] = c4.w;
    } else {
        for (int e = e0; e < N_EDGES; ++e)
            csr_col[rowptr[ei[e]] + rank[e]] = ei[N_EDGES + e];
    }
}

// ---------------- transpose W [OUTF][HIDDEN] -> Wt [HIDDEN][OUTF] in global ----------------
__global__ void wtrans_kernel(const float* __restrict__ W, float* __restrict__ Wt) {
    int i = blockIdx.x * blockDim.x + threadIdx.x;
    if (i < HIDDEN * OUTF) {
        int o = i / HIDDEN, k = i % HIDDEN;
        Wt[k * OUTF + o] = W[i];
    }
}

// ---------------- gemm: y0(bf16) = x @ W^T  (64x64 tile, K staged 4x32) ----------------
#define GR    64
#define BK    32
#define HSP   36   // hs row stride (pad 4)
#define WTP   68   // wt row stride (pad 4)
__global__ __launch_bounds__(256) void gemm_kernel(const float* __restrict__ x,
                                                   const float* __restrict__ Wt,
                                                   unsigned short* __restrict__ y0) {
    __shared__ float hs[GR * HSP];   // [row][kk]
    __shared__ float wt[BK * WTP];   // [kk][o]
    int tid = threadIdx.x;
    int rowBase = blockIdx.x * GR;

    int o4 = (tid & 15) * 4;
    int rq = (tid >> 4) * 4;
    float4 a0 = {0,0,0,0}, a1 = {0,0,0,0}, a2 = {0,0,0,0}, a3 = {0,0,0,0};

    for (int kt = 0; kt < HIDDEN / BK; ++kt) {
        if (kt) __syncthreads();
        int kbase = kt * BK;
        #pragma unroll
        for (int t = 0; t < 2; ++t) {
            int f = tid + t * 256;
            int r = f >> 3, c4 = (f & 7) * 4;
            int row = rowBase + r;
            float4 v = (row < N_NODES) ? *(const float4*)(x + (size_t)row * HIDDEN + kbase + c4)
                                       : make_float4(0.f, 0.f, 0.f, 0.f);
            *(float4*)&hs[r * HSP + c4] = v;
        }
        #pragma unroll
        for (int t = 0; t < 2; ++t) {
            int f = tid + t * 256;
            int k = f >> 4, c4 = (f & 15) * 4;
            float4 v = *(const float4*)(Wt + (size_t)(kbase + k) * OUTF + c4);
            *(float4*)&wt[k * WTP + c4] = v;
        }
        __syncthreads();
        #pragma unroll 8
        for (int kk = 0; kk < BK; ++kk) {
            float4 wv = *(const float4*)&wt[kk * WTP + o4];
            float h0 = hs[(rq + 0) * HSP + kk];
            float h1 = hs[(rq + 1) * HSP + kk];
            float h2 = hs[(rq + 2) * HSP + kk];
            float h3 = hs[(rq + 3) * HSP + kk];
            a0.x += h0 * wv.x; a0.y += h0 * wv.y; a0.z += h0 * wv.z; a0.w += h0 * wv.w;
            a1.x += h1 * wv.x; a1.y += h1 * wv.y; a1.z += h1 * wv.z; a1.w += h1 * wv.w;
            a2.x += h2 * wv.x; a2.y += h2 * wv.y; a2.z += h2 * wv.z; a2.w += h2 * wv.w;
            a3.x += h3 * wv.x; a3.y += h3 * wv.y; a3.z += h3 * wv.z; a3.w += h3 * wv.w;
        }
    }
    int row = rowBase + rq;
    ushort4 s0 = {f2bf(a0.x), f2bf(a0.y), f2bf(a0.z), f2bf(a0.w)};
    ushort4 s1 = {f2bf(a1.x), f2bf(a1.y), f2bf(a1.z), f2bf(a1.w)};
    ushort4 s2 = {f2bf(a2.x), f2bf(a2.y), f2bf(a2.z), f2bf(a2.w)};
    ushort4 s3 = {f2bf(a3.x), f2bf(a3.y), f2bf(a3.z), f2bf(a3.w)};
    if (row + 0 < N_NODES) *(ushort4*)&y0[(size_t)(row + 0) * OUTF + o4] = s0;
    if (row + 1 < N_NODES) *(ushort4*)&y0[(size_t)(row + 1) * OUTF + o4] = s1;
    if (row + 2 < N_NODES) *(ushort4*)&y0[(size_t)(row + 2) * OUTF + o4] = s2;
    if (row + 3 < N_NODES) *(ushort4*)&y0[(size_t)(row + 3) * OUTF + o4] = s3;
}

// ---------------- pull propagate on bf16 64-wide features: one wave per node ----------------
__global__ __launch_bounds__(256) void pull_kernel(const int* __restrict__ rowptr,
                                                   const int* __restrict__ csr_col,
                                                   const float* __restrict__ dinv,
                                                   const unsigned short* __restrict__ ysrc,
                                                   unsigned short* __restrict__ ydst) {
    int node = blockIdx.x * 4 + (threadIdx.x >> 6);
    int lane = threadIdx.x & 63;
    if (node >= N_NODES) return;
    int s = rowptr[node];
    int e = rowptr[node + 1];
    float dr = dinv[node];
    float acc = 0.f;
    int i = s;
    for (; i + 3 < e; i += 4) {
        int c0 = csr_col[i];
        int c1 = csr_col[i + 1];
        int c2 = csr_col[i + 2];
        int c3 = csr_col[i + 3];
        float w0 = dinv[c0], w1 = dinv[c1], w2 = dinv[c2], w3 = dinv[c3];
        float v0 = bf2f(ysrc[(size_t)c0 * OUTF + lane]);
        float v1 = bf2f(ysrc[(size_t)c1 * OUTF + lane]);
        float v2 = bf2f(ysrc[(size_t)c2 * OUTF + lane]);
        float v3 = bf2f(ysrc[(size_t)c3 * OUTF + lane]);
        acc += w0 * v0 + w1 * v1;
        acc += w2 * v2 + w3 * v3;
    }
    for (; i < e; ++i) {
        int c0 = csr_col[i];
        acc += dinv[c0] * bf2f(ysrc[(size_t)c0 * OUTF + lane]);
    }
    ydst[(size_t)node * OUTF + lane] = f2bf(acc * dr);
}

// ---------------- fused layer-3 pull + mean + bias (fp32 out) ----------------
__global__ __launch_bounds__(256) void pull_merge_kernel(const int* __restrict__ rowptr,
                                                         const int* __restrict__ csr_col,
                                                         const float* __restrict__ dinv,
                                                         const unsigned short* __restrict__ y0,
                                                         const unsigned short* __restrict__ y1,
                                                         const unsigned short* __restrict__ y2,
                                                         const float* __restrict__ b,
                                                         float* __restrict__ out) {
    int node = blockIdx.x * 4 + (threadIdx.x >> 6);
    int lane = threadIdx.x & 63;
    if (node >= N_NODES) return;
    int s = rowptr[node];
    int e = rowptr[node + 1];
    float dr = dinv[node];
    float acc = 0.f;
    int i = s;
    for (; i + 3 < e; i += 4) {
        int c0 = csr_col[i];
        int c1 = csr_col[i + 1];
        int c2 = csr_col[i + 2];
        int c3 = csr_col[i + 3];
        float w0 = dinv[c0], w1 = dinv[c1], w2 = dinv[c2], w3 = dinv[c3];
        float v0 = bf2f(y2[(size_t)c0 * OUTF + lane]);
        float v1 = bf2f(y2[(size_t)c1 * OUTF + lane]);
        float v2 = bf2f(y2[(size_t)c2 * OUTF + lane]);
        float v3 = bf2f(y2[(size_t)c3 * OUTF + lane]);
        acc += w0 * v0 + w1 * v1;
        acc += w2 * v2 + w3 * v3;
    }
    for (; i < e; ++i) {
        int c0 = csr_col[i];
        acc += dinv[c0] * bf2f(y2[(size_t)c0 * OUTF + lane]);
    }
    size_t idx = (size_t)node * OUTF + lane;
    float sum = bf2f(y0[idx]) + bf2f(y1[idx]) + bf2f(y2[idx]) + acc * dr;
    out[idx] = 0.25f * sum + b[lane];
}

extern "C" void kernel_launch(void* const* d_in, const int* in_sizes, int n_in,
                              void* d_out, int out_size, void* d_ws, size_t ws_size,
                              hipStream_t stream) {
    const float* x  = (const float*)d_in[0];
    const int*   ei = (const int*)d_in[1];     // int32, [2, E] flat
    const float* W  = (const float*)d_in[2];
    const float* b  = (const float*)d_in[3];
    float*       out = (float*)d_out;

    // workspace layout
    unsigned short* y0 = (unsigned short*)d_ws;               // N*64 bf16
    unsigned short* y1 = y0 + (size_t)N_NODES * OUTF;         // N*64 bf16
    unsigned short* y2 = y1 + (size_t)N_NODES * OUTF;         // N*64 bf16
    float* Wt      = (float*)(y2 + (size_t)N_NODES * OUTF);   // 8192 f32
    int*   csrcol  = (int*)(Wt + HIDDEN * OUTF);              // E
    int*   rank    = csrcol + N_EDGES;                        // E
    int*   rowptr  = rank + N_EDGES;                          // N+1
    int*   cnt     = rowptr + (N_NODES + 1);                  // N
    float* dinv    = (float*)(cnt + N_NODES);                 // N
    int*   tileSum = (int*)(dinv + N_NODES);                  // NTILES
    int*   tileOff = tileSum + NTILES;                        // NTILES

    const int BLK = 256;
    const int edge4Blocks = (N_EDGES / 4 + BLK - 1) / BLK;  // 1563
    const int nodeBlocks  = (N_NODES + BLK - 1) / BLK;
    const int cntZero4    = (N_NODES / 4 + BLK - 1) / BLK;
    const int pullBlocks  = (N_NODES + 3) / 4;
    const int gemmBlocks  = (N_NODES + GR - 1) / GR;        // 1563

    // ---- CSR build ----
    zero_kernel<<<cntZero4, BLK, 0, stream>>>((int4*)cnt, N_NODES / 4);
    count_kernel<<<edge4Blocks, BLK, 0, stream>>>(ei, cnt, rank);
    scan_tiles_kernel<<<NTILES, BLK, 0, stream>>>(cnt, rowptr, tileSum);
    scan_sums_kernel<<<1, 128, 0, stream>>>(tileSum, tileOff, rowptr);
    finalize_kernel<<<nodeBlocks, BLK, 0, stream>>>(cnt, tileOff, rowptr, dinv);
    fill_kernel<<<edge4Blocks, BLK, 0, stream>>>(ei, rowptr, rank, csrcol);

    // ---- project once, propagate in bf16 64-dim, fuse final layer with merge ----
    wtrans_kernel<<<(HIDDEN * OUTF + BLK - 1) / BLK, BLK, 0, stream>>>(W, Wt);
    gemm_kernel<<<gemmBlocks, BLK, 0, stream>>>(x, Wt, y0);
    pull_kernel<<<pullBlocks, BLK, 0, stream>>>(rowptr, csrcol, dinv, y0, y1);
    pull_kernel<<<pullBlocks, BLK, 0, stream>>>(rowptr, csrcol, dinv, y1, y2);
    pull_merge_kernel<<<pullBlocks, BLK, 0, stream>>>(rowptr, csrcol, dinv, y0, y1, y2, b, out);
}

// Round 9
// 376.342 us; speedup vs baseline: 23.1561x; 1.0999x over previous
//
#include <hip/hip_runtime.h>

#define N_NODES 100000
#define N_EDGES 1600000
#define HIDDEN  128
#define OUTF    64
#define TILE    1024
#define NTILES  ((N_NODES + TILE - 1) / TILE)   // 98

// ---------------- bf16 helpers (RTE) ----------------
__device__ __forceinline__ unsigned short f2bf(float f) {
    unsigned u = __float_as_uint(f);
    u += 0x7fffu + ((u >> 16) & 1u);
    return (unsigned short)(u >> 16);
}
__device__ __forceinline__ float bf2f(unsigned short h) {
    return __uint_as_float(((unsigned)h) << 16);
}
// unpack packed pair of bf16 (little-endian: lo = even feature)
__device__ __forceinline__ float2 bfp2f(unsigned p) {
    return make_float2(__uint_as_float(p << 16), __uint_as_float(p & 0xffff0000u));
}

// ---------------- zero ints ----------------
__global__ void zero_kernel(int4* p, int n4) {
    int i = blockIdx.x * blockDim.x + threadIdx.x;
    if (i < n4) p[i] = make_int4(0, 0, 0, 0);
}

// ---------------- count degrees; atomic return value IS the intra-row rank ----------------
__global__ void count_kernel(const int* __restrict__ ei,
                             int* __restrict__ cnt,
                             int* __restrict__ rank) {
    int t  = blockIdx.x * blockDim.x + threadIdx.x;
    int e0 = t * 4;
    if (e0 + 3 < N_EDGES) {
        int4 r4 = *(const int4*)(ei + e0);
        int k0 = atomicAdd(&cnt[r4.x], 1);
        int k1 = atomicAdd(&cnt[r4.y], 1);
        int k2 = atomicAdd(&cnt[r4.z], 1);
        int k3 = atomicAdd(&cnt[r4.w], 1);
        *(int4*)(rank + e0) = make_int4(k0, k1, k2, k3);
    } else {
        for (int e = e0; e < N_EDGES; ++e) rank[e] = atomicAdd(&cnt[ei[e]], 1);
    }
}

// ---------------- scan stage 1: per-tile exclusive scan ----------------
__global__ __launch_bounds__(256) void scan_tiles_kernel(const int* __restrict__ cnt,
                                                         int* __restrict__ rowptr,
                                                         int* __restrict__ tileSum) {
    __shared__ int ps[256];
    int tid  = threadIdx.x;
    int base = blockIdx.x * TILE + tid * 4;
    int a0 = 0, a1 = 0, a2 = 0, a3 = 0;
    if (base + 3 < N_NODES) {
        int4 v = *(const int4*)(cnt + base);
        a0 = v.x; a1 = v.y; a2 = v.z; a3 = v.w;
    } else {
        if (base + 0 < N_NODES) a0 = cnt[base + 0];
        if (base + 1 < N_NODES) a1 = cnt[base + 1];
        if (base + 2 < N_NODES) a2 = cnt[base + 2];
        if (base + 3 < N_NODES) a3 = cnt[base + 3];
    }
    int s = a0 + a1 + a2 + a3;
    ps[tid] = s;
    __syncthreads();
    for (int off = 1; off < 256; off <<= 1) {
        int t = (tid >= off) ? ps[tid - off] : 0;
        __syncthreads();
        ps[tid] += t;
        __syncthreads();
    }
    int ex = ps[tid] - s;
    int e0 = ex, e1 = e0 + a0, e2 = e1 + a1, e3 = e2 + a2;
    if (base + 3 < N_NODES) {
        *(int4*)(rowptr + base) = make_int4(e0, e1, e2, e3);
    } else {
        if (base + 0 < N_NODES) rowptr[base + 0] = e0;
        if (base + 1 < N_NODES) rowptr[base + 1] = e1;
        if (base + 2 < N_NODES) rowptr[base + 2] = e2;
        if (base + 3 < N_NODES) rowptr[base + 3] = e3;
    }
    if (tid == 255) tileSum[blockIdx.x] = ps[255];
}

// ---------------- scan stage 2: scan tile sums ----------------
__global__ __launch_bounds__(128) void scan_sums_kernel(const int* __restrict__ tileSum,
                                                        int* __restrict__ tileOff,
                                                        int* __restrict__ rowptr) {
    __shared__ int ps[128];
    int tid = threadIdx.x;
    int v = (tid < NTILES) ? tileSum[tid] : 0;
    ps[tid] = v;
    __syncthreads();
    for (int off = 1; off < 128; off <<= 1) {
        int t = (tid >= off) ? ps[tid - off] : 0;
        __syncthreads();
        ps[tid] += t;
        __syncthreads();
    }
    if (tid < NTILES) tileOff[tid] = ps[tid] - v;
    if (tid == 127) rowptr[N_NODES] = ps[127];
}

// ---------------- scan stage 3: finalize rowptr, dinv, rdinv ----------------
__global__ void finalize_kernel(const int* __restrict__ cnt,
                                const int* __restrict__ tileOff,
                                int* __restrict__ rowptr,
                                float* __restrict__ dinv,
                                float* __restrict__ rdinv) {
    int i = blockIdx.x * blockDim.x + threadIdx.x;
    if (i < N_NODES) {
        rowptr[i]  += tileOff[i / TILE];
        float d     = fmaxf((float)cnt[i], 1.0f);
        dinv[i]     = rsqrtf(d);
        rdinv[i]    = sqrtf(d);
    }
}

// ---------------- fill CSR columns: no atomics, 4-edge ILP ----------------
__global__ void fill_kernel(const int* __restrict__ ei,
                            const int* __restrict__ rowptr,
                            const int* __restrict__ rank,
                            int* __restrict__ csr_col) {
    int t  = blockIdx.x * blockDim.x + threadIdx.x;
    int e0 = t * 4;
    if (e0 + 3 < N_EDGES) {
        int4 r4 = *(const int4*)(ei + e0);
        int4 c4 = *(const int4*)(ei + N_EDGES + e0);
        int4 k4 = *(const int4*)(rank + e0);
        csr_col[rowptr[r4.x] + k4.x] = c4.x;
        csr_col[rowptr[r4.y] + k4.y] = c4.y;
        csr_col[rowptr[r4.z] + k4.z] = c4.z;
        csr_col[rowptr[r4.w] + k4.w] = c4.w;
    } else {
        for (int e = e0; e < N_EDGES; ++e)
            csr_col[rowptr[ei[e]] + rank[e]] = ei[N_EDGES + e];
    }
}

// ---------------- transpose W [OUTF][HIDDEN] -> Wt [HIDDEN][OUTF] ----------------
__global__ void wtrans_kernel(const float* __restrict__ W, float* __restrict__ Wt) {
    int i = blockIdx.x * blockDim.x + threadIdx.x;
    if (i < HIDDEN * OUTF) {
        int o = i / HIDDEN, k = i % HIDDEN;
        Wt[k * OUTF + o] = W[i];
    }
}

// ---------------- gemm: z0(bf16) = dinv .* (x @ W^T) ----------------
#define GR    64
#define BK    32
#define HSP   36
#define WTP   68
__global__ __launch_bounds__(256) void gemm_kernel(const float* __restrict__ x,
                                                   const float* __restrict__ Wt,
                                                   const float* __restrict__ dinv,
                                                   unsigned short* __restrict__ z0) {
    __shared__ float hs[GR * HSP];
    __shared__ float wt[BK * WTP];
    int tid = threadIdx.x;
    int rowBase = blockIdx.x * GR;

    int o4 = (tid & 15) * 4;
    int rq = (tid >> 4) * 4;
    float4 a0 = {0,0,0,0}, a1 = {0,0,0,0}, a2 = {0,0,0,0}, a3 = {0,0,0,0};

    for (int kt = 0; kt < HIDDEN / BK; ++kt) {
        if (kt) __syncthreads();
        int kbase = kt * BK;
        #pragma unroll
        for (int t = 0; t < 2; ++t) {
            int f = tid + t * 256;
            int r = f >> 3, c4 = (f & 7) * 4;
            int row = rowBase + r;
            float4 v = (row < N_NODES) ? *(const float4*)(x + (size_t)row * HIDDEN + kbase + c4)
                                       : make_float4(0.f, 0.f, 0.f, 0.f);
            *(float4*)&hs[r * HSP + c4] = v;
        }
        #pragma unroll
        for (int t = 0; t < 2; ++t) {
            int f = tid + t * 256;
            int k = f >> 4, c4 = (f & 15) * 4;
            float4 v = *(const float4*)(Wt + (size_t)(kbase + k) * OUTF + c4);
            *(float4*)&wt[k * WTP + c4] = v;
        }
        __syncthreads();
        #pragma unroll 8
        for (int kk = 0; kk < BK; ++kk) {
            float4 wv = *(const float4*)&wt[kk * WTP + o4];
            float h0 = hs[(rq + 0) * HSP + kk];
            float h1 = hs[(rq + 1) * HSP + kk];
            float h2 = hs[(rq + 2) * HSP + kk];
            float h3 = hs[(rq + 3) * HSP + kk];
            a0.x += h0 * wv.x; a0.y += h0 * wv.y; a0.z += h0 * wv.z; a0.w += h0 * wv.w;
            a1.x += h1 * wv.x; a1.y += h1 * wv.y; a1.z += h1 * wv.z; a1.w += h1 * wv.w;
            a2.x += h2 * wv.x; a2.y += h2 * wv.y; a2.z += h2 * wv.z; a2.w += h2 * wv.w;
            a3.x += h3 * wv.x; a3.y += h3 * wv.y; a3.z += h3 * wv.z; a3.w += h3 * wv.w;
        }
    }
    int row = rowBase + rq;
    #pragma unroll
    for (int r = 0; r < 4; ++r) {
        if (row + r < N_NODES) {
            float d = dinv[row + r];
            float4 a = (r == 0) ? a0 : (r == 1) ? a1 : (r == 2) ? a2 : a3;
            ushort4 s = {f2bf(a.x * d), f2bf(a.y * d), f2bf(a.z * d), f2bf(a.w * d)};
            *(ushort4*)&z0[(size_t)(row + r) * OUTF + o4] = s;
        }
    }
}

// ---------------- pull on z (=dinv*y): zdst[n] = dinv[n]^2 * sum_c zsrc[c] ----------------
// Half-wave edge pairing: lanes 0-31 take even edges, 32-63 odd; each lane holds a
// bf16 feature PAIR (ushort2). One gather instruction covers 2 edges.
__global__ __launch_bounds__(256) void pull_kernel(const int* __restrict__ rowptr,
                                                   const int* __restrict__ csr_col,
                                                   const float* __restrict__ dinv,
                                                   const unsigned short* __restrict__ zsrc,
                                                   unsigned short* __restrict__ zdst) {
    int node = blockIdx.x * 4 + (threadIdx.x >> 6);
    int lane = threadIdx.x & 63;
    if (node >= N_NODES) return;
    int half = lane >> 5;          // edge parity
    int fp   = (lane & 31) * 2;    // feature pair base
    int s = rowptr[node];
    int e = rowptr[node + 1];
    float2 acc = make_float2(0.f, 0.f);
    int i = s;
    for (; i + 7 < e; i += 8) {
        int c0 = csr_col[i     + half];
        int c1 = csr_col[i + 2 + half];
        int c2 = csr_col[i + 4 + half];
        int c3 = csr_col[i + 6 + half];
        unsigned p0 = *(const unsigned*)(zsrc + (size_t)c0 * OUTF + fp);
        unsigned p1 = *(const unsigned*)(zsrc + (size_t)c1 * OUTF + fp);
        unsigned p2 = *(const unsigned*)(zsrc + (size_t)c2 * OUTF + fp);
        unsigned p3 = *(const unsigned*)(zsrc + (size_t)c3 * OUTF + fp);
        float2 v0 = bfp2f(p0), v1 = bfp2f(p1), v2 = bfp2f(p2), v3 = bfp2f(p3);
        acc.x += v0.x + v1.x; acc.y += v0.y + v1.y;
        acc.x += v2.x + v3.x; acc.y += v2.y + v3.y;
    }
    for (; i + 1 < e; i += 2) {
        int c = csr_col[i + half];
        float2 v = bfp2f(*(const unsigned*)(zsrc + (size_t)c * OUTF + fp));
        acc.x += v.x; acc.y += v.y;
    }
    if (i < e && half == 0) {
        int c = csr_col[i];
        float2 v = bfp2f(*(const unsigned*)(zsrc + (size_t)c * OUTF + fp));
        acc.x += v.x; acc.y += v.y;
    }
    acc.x += __shfl_xor(acc.x, 32);
    acc.y += __shfl_xor(acc.y, 32);
    if (lane < 32) {
        float dn = dinv[node];
        float zs = dn * dn;
        ushort2 o = {f2bf(acc.x * zs), f2bf(acc.y * zs)};
        *(ushort2*)(zdst + (size_t)node * OUTF + fp) = o;
    }
}

// ---------------- fused layer-3 pull + mean + bias (fp32 out) ----------------
// out[n] = 0.25*((z0+z1+z2)[n]*rdinv[n] + dinv[n]*sum_c z2[c]) + b
__global__ __launch_bounds__(256) void pull_merge_kernel(const int* __restrict__ rowptr,
                                                         const int* __restrict__ csr_col,
                                                         const float* __restrict__ dinv,
                                                         const float* __restrict__ rdinv,
                                                         const unsigned short* __restrict__ z0,
                                                         const unsigned short* __restrict__ z1,
                                                         const unsigned short* __restrict__ z2,
                                                         const float* __restrict__ b,
                                                         float* __restrict__ out) {
    int node = blockIdx.x * 4 + (threadIdx.x >> 6);
    int lane = threadIdx.x & 63;
    if (node >= N_NODES) return;
    int half = lane >> 5;
    int fp   = (lane & 31) * 2;
    int s = rowptr[node];
    int e = rowptr[node + 1];
    float2 acc = make_float2(0.f, 0.f);
    int i = s;
    for (; i + 7 < e; i += 8) {
        int c0 = csr_col[i     + half];
        int c1 = csr_col[i + 2 + half];
        int c2 = csr_col[i + 4 + half];
        int c3 = csr_col[i + 6 + half];
        unsigned p0 = *(const unsigned*)(z2 + (size_t)c0 * OUTF + fp);
        unsigned p1 = *(const unsigned*)(z2 + (size_t)c1 * OUTF + fp);
        unsigned p2 = *(const unsigned*)(z2 + (size_t)c2 * OUTF + fp);
        unsigned p3 = *(const unsigned*)(z2 + (size_t)c3 * OUTF + fp);
        float2 v0 = bfp2f(p0), v1 = bfp2f(p1), v2 = bfp2f(p2), v3 = bfp2f(p3);
        acc.x += v0.x + v1.x; acc.y += v0.y + v1.y;
        acc.x += v2.x + v3.x; acc.y += v2.y + v3.y;
    }
    for (; i + 1 < e; i += 2) {
        int c = csr_col[i + half];
        float2 v = bfp2f(*(const unsigned*)(z2 + (size_t)c * OUTF + fp));
        acc.x += v.x; acc.y += v.y;
    }
    if (i < e && half == 0) {
        int c = csr_col[i];
        float2 v = bfp2f(*(const unsigned*)(z2 + (size_t)c * OUTF + fp));
        acc.x += v.x; acc.y += v.y;
    }
    acc.x += __shfl_xor(acc.x, 32);
    acc.y += __shfl_xor(acc.y, 32);
    if (lane < 32) {
        size_t idx = (size_t)node * OUTF + fp;
        float rd = rdinv[node];
        float dn = dinv[node];
        float2 s0 = bfp2f(*(const unsigned*)(z0 + idx));
        float2 s1 = bfp2f(*(const unsigned*)(z1 + idx));
        float2 s2 = bfp2f(*(const unsigned*)(z2 + idx));
        float2 bv = *(const float2*)(b + fp);
        float2 r;
        r.x = 0.25f * ((s0.x + s1.x + s2.x) * rd + dn * acc.x) + bv.x;
        r.y = 0.25f * ((s0.y + s1.y + s2.y) * rd + dn * acc.y) + bv.y;
        *(float2*)(out + idx) = r;
    }
}

extern "C" void kernel_launch(void* const* d_in, const int* in_sizes, int n_in,
                              void* d_out, int out_size, void* d_ws, size_t ws_size,
                              hipStream_t stream) {
    const float* x  = (const float*)d_in[0];
    const int*   ei = (const int*)d_in[1];     // int32, [2, E] flat
    const float* W  = (const float*)d_in[2];
    const float* b  = (const float*)d_in[3];
    float*       out = (float*)d_out;

    // workspace layout
    unsigned short* z0 = (unsigned short*)d_ws;               // N*64 bf16
    unsigned short* z1 = z0 + (size_t)N_NODES * OUTF;         // N*64 bf16
    unsigned short* z2 = z1 + (size_t)N_NODES * OUTF;         // N*64 bf16
    float* Wt      = (float*)(z2 + (size_t)N_NODES * OUTF);   // 8192 f32
    int*   csrcol  = (int*)(Wt + HIDDEN * OUTF);              // E
    int*   rank    = csrcol + N_EDGES;                        // E
    int*   rowptr  = rank + N_EDGES;                          // N+1
    int*   cnt     = rowptr + (N_NODES + 1);                  // N
    float* dinv    = (float*)(cnt + N_NODES);                 // N
    float* rdinv   = dinv + N_NODES;                          // N
    int*   tileSum = (int*)(rdinv + N_NODES);                 // NTILES
    int*   tileOff = tileSum + NTILES;                        // NTILES

    const int BLK = 256;
    const int edge4Blocks = (N_EDGES / 4 + BLK - 1) / BLK;  // 1563
    const int nodeBlocks  = (N_NODES + BLK - 1) / BLK;
    const int cntZero4    = (N_NODES / 4 + BLK - 1) / BLK;
    const int pullBlocks  = (N_NODES + 3) / 4;
    const int gemmBlocks  = (N_NODES + GR - 1) / GR;        // 1563

    // ---- CSR build ----
    zero_kernel<<<cntZero4, BLK, 0, stream>>>((int4*)cnt, N_NODES / 4);
    count_kernel<<<edge4Blocks, BLK, 0, stream>>>(ei, cnt, rank);
    scan_tiles_kernel<<<NTILES, BLK, 0, stream>>>(cnt, rowptr, tileSum);
    scan_sums_kernel<<<1, 128, 0, stream>>>(tileSum, tileOff, rowptr);
    finalize_kernel<<<nodeBlocks, BLK, 0, stream>>>(cnt, tileOff, rowptr, dinv, rdinv);
    fill_kernel<<<edge4Blocks, BLK, 0, stream>>>(ei, rowptr, rank, csrcol);

    // ---- project once, propagate z in bf16, fuse final layer with merge ----
    wtrans_kernel<<<(HIDDEN * OUTF + BLK - 1) / BLK, BLK, 0, stream>>>(W, Wt);
    gemm_kernel<<<gemmBlocks, BLK, 0, stream>>>(x, Wt, dinv, z0);
    pull_kernel<<<pullBlocks, BLK, 0, stream>>>(rowptr, csrcol, dinv, z0, z1);
    pull_kernel<<<pullBlocks, BLK, 0, stream>>>(rowptr, csrcol, dinv, z1, z2);
    pull_merge_kernel<<<pullBlocks, BLK, 0, stream>>>(rowptr, csrcol, dinv, rdinv,
                                                      z0, z1, z2, b, out);
}